// Round 1
// baseline (655.575 us; speedup 1.0000x reference)
//
#include <hip/hip_runtime.h>
#include <hip/hip_bf16.h>
#include <math.h>

// ---------------------------------------------------------------------------
// MotionCorrect: FFT-based NCC on 512x512x32 volume.
//   out = [sh_x, sh_y, sh_z, rolled_cc(512*512*32), ncc(21*21*5)]
// ---------------------------------------------------------------------------

#define XD 512
#define YD 512
#define ZD 32
#define NTOT 8388608            // 512*512*32
#define NLINES 262144           // 512*512
#define OUT_ROLL_OFF 3
#define OUT_NCC_OFF 8388611     // 3 + NTOT
#define WIN_PROD 6777792.0      // 492*492*28
#define EPSV 1e-8

// ws layout (bytes)
#define WS_HC_OFF 0UL                       // double2[NTOT] = 134217728 B
#define WS_ZS1_OFF 0UL                      // overlaps Hc (used before Hc is written)
#define WS_ZS2_OFF 10485760UL
#define WS_YS1_OFF 20971520UL
#define WS_YS2_OFF 21401600UL
#define WS_STATS_OFF 134217728UL            // double[8]
#define WS_DENOM_OFF 134217792UL            // float[2205]

// twiddles for FFT-32: cos/sin(2*pi*k/32), k=0..15
static constexpr double W32C_[16] = {
    1.0, 0.98078528040323044913, 0.92387953251128675613, 0.83146961230254523708,
    0.70710678118654752440, 0.55557023301960222474, 0.38268343236508977173, 0.19509032201612826785,
    0.0, -0.19509032201612826785, -0.38268343236508977173, -0.55557023301960222474,
    -0.70710678118654752440, -0.83146961230254523708, -0.92387953251128675613, -0.98078528040323044913};
static constexpr double W32S_[16] = {
    0.0, 0.19509032201612826785, 0.38268343236508977173, 0.55557023301960222474,
    0.70710678118654752440, 0.83146961230254523708, 0.92387953251128675613, 0.98078528040323044913,
    1.0, 0.98078528040323044913, 0.92387953251128675613, 0.83146961230254523708,
    0.70710678118654752440, 0.55557023301960222474, 0.38268343236508977173, 0.19509032201612826785};

// per-thread radix-2 FFT of length 32, fully unrolled (indices constant-folded)
// INV=0: DIF, natural in -> bit-reversed out, exp(-i) twiddles
// INV=1: DIT, bit-reversed in -> natural out, exp(+i) twiddles
template <int INV>
__device__ __forceinline__ void fft32(double2* a) {
    if (INV == 0) {
#pragma unroll
        for (int s = 0; s < 5; ++s) {
            const int h = 16 >> s;
#pragma unroll
            for (int j = 0; j < 16; ++j) {
                const int t = j & (h - 1);
                const int i0 = ((j >> (4 - s)) << (5 - s)) + t;
                const int i1 = i0 + h;
                double2 u = a[i0], v = a[i1];
                a[i0] = make_double2(u.x + v.x, u.y + v.y);
                double dx = u.x - v.x, dy = u.y - v.y;
                const double wc = W32C_[t << s];
                const double ws = -W32S_[t << s];
                a[i1] = make_double2(dx * wc - dy * ws, dx * ws + dy * wc);
            }
        }
    } else {
#pragma unroll
        for (int s = 0; s < 5; ++s) {
            const int h = 1 << s;
#pragma unroll
            for (int j = 0; j < 16; ++j) {
                const int t = j & (h - 1);
                const int i0 = ((j >> s) << (s + 1)) + t;
                const int i1 = i0 + h;
                const double wc = W32C_[t << (4 - s)];
                const double ws = W32S_[t << (4 - s)];
                double2 u = a[i0], vr = a[i1];
                double2 v = make_double2(vr.x * wc - vr.y * ws, vr.x * ws + vr.y * wc);
                a[i0] = make_double2(u.x + v.x, u.y + v.y);
                a[i1] = make_double2(u.x - v.x, u.y - v.y);
            }
        }
    }
}

// bit-reversed-storage mirror of frequency negation: involution per dimension
__device__ __forceinline__ int mir_br(int b) {
    if (b == 0) return 0;
    int s = 31 - __clz(b);
    return (3 << s) - 1 - b;
}

// ---------------------------------------------------------------------------
// K1: global sums: sum(img), sum(tpl), sum(tpl^2)
__global__ __launch_bounds__(256) void k_reduce_stats(const float* __restrict__ img,
                                                      const float* __restrict__ tpl,
                                                      double* __restrict__ stats) {
    double si = 0, st = 0, st2 = 0;
    const int stride = gridDim.x * blockDim.x;
    for (int i = blockIdx.x * blockDim.x + threadIdx.x; i < NTOT; i += stride) {
        si += (double)img[i];
        double t = (double)tpl[i];
        st += t;
        st2 += t * t;
    }
    __shared__ double s0[256], s1[256], s2[256];
    int tid = threadIdx.x;
    s0[tid] = si; s1[tid] = st; s2[tid] = st2;
    __syncthreads();
    for (int s = 128; s > 0; s >>= 1) {
        if (tid < s) {
            s0[tid] += s0[tid + s];
            s1[tid] += s1[tid + s];
            s2[tid] += s2[tid + s];
        }
        __syncthreads();
    }
    if (tid == 0) {
        atomicAdd(&stats[0], s0[0]);
        atomicAdd(&stats[1], s1[0]);
        atomicAdd(&stats[2], s2[0]);
    }
}

__global__ void k_finalize_stats(double* stats) {
    double mu_i = stats[0] / (double)NTOT;
    double mu_t = stats[1] / (double)NTOT;
    stats[3] = mu_i;
    stats[4] = mu_t;
    stats[5] = stats[2] - (double)NTOT * mu_t * mu_t + EPSV;  // tpl_var
}

// ---------------------------------------------------------------------------
// K2: z-direction sliding-window sums (window 28 of 32 -> 5) for img and img^2
__global__ __launch_bounds__(256) void k_winz(const float* __restrict__ img,
                                              double* __restrict__ zs1,
                                              double* __restrict__ zs2) {
    int line = blockIdx.x * blockDim.x + threadIdx.x;  // x*512+y
    long b = (long)line << 5;
    float v[32];
    const float4* p4 = (const float4*)(img + b);
#pragma unroll
    for (int q = 0; q < 8; ++q) {
        float4 f = p4[q];
        v[q * 4 + 0] = f.x; v[q * 4 + 1] = f.y; v[q * 4 + 2] = f.z; v[q * 4 + 3] = f.w;
    }
    double s1 = 0, s2 = 0;
#pragma unroll
    for (int z = 0; z < 28; ++z) {
        double t = (double)v[z];
        s1 += t;
        s2 += t * t;
    }
    long ob = (long)line * 5;
    zs1[ob] = s1; zs2[ob] = s2;
#pragma unroll
    for (int k = 1; k <= 4; ++k) {
        double a = (double)v[27 + k], r = (double)v[k - 1];
        s1 += a - r;
        s2 += a * a - r * r;
        zs1[ob + k] = s1; zs2[ob + k] = s2;
    }
}

// K3: y-direction sliding window (492 of 512 -> 21)
__global__ __launch_bounds__(256) void k_winy(const double* __restrict__ zs1,
                                              const double* __restrict__ zs2,
                                              double* __restrict__ ys1,
                                              double* __restrict__ ys2) {
    int t = blockIdx.x * blockDim.x + threadIdx.x;
    if (t >= 2560) return;
    int x = t / 5, c = t % 5;
    long base = (long)x * 512 * 5 + c;
    double s1 = 0, s2 = 0;
    for (int y = 0; y < 492; ++y) {
        s1 += zs1[base + (long)y * 5];
        s2 += zs2[base + (long)y * 5];
    }
    long ob = (long)x * 105 + c;
    ys1[ob] = s1; ys2[ob] = s2;
    for (int k = 1; k <= 20; ++k) {
        s1 += zs1[base + (long)(491 + k) * 5] - zs1[base + (long)(k - 1) * 5];
        s2 += zs2[base + (long)(491 + k) * 5] - zs2[base + (long)(k - 1) * 5];
        ys1[ob + (long)k * 5] = s1;
        ys2[ob + (long)k * 5] = s2;
    }
}

// K4: x-direction sliding window (492 of 512 -> 21) + denominator
__global__ __launch_bounds__(128) void k_winx_denom(const double* __restrict__ ys1,
                                                    const double* __restrict__ ys2,
                                                    const double* __restrict__ stats,
                                                    float* __restrict__ denom) {
    int t = blockIdx.x * blockDim.x + threadIdx.x;
    if (t >= 105) return;
    double tpl_var = stats[5];
    double s1 = 0, s2 = 0;
    for (int x = 0; x < 492; ++x) {
        s1 += ys1[(long)x * 105 + t];
        s2 += ys2[(long)x * 105 + t];
    }
    const double wm = 1.0 / WIN_PROD;
    for (int a = 0; a < 21; ++a) {
        double m1 = s1 * wm, m2 = s2 * wm;
        double iv = m2 - (m1 * m1) / (double)NTOT + EPSV;
        if (iv < 0) iv = 0;
        denom[a * 105 + t] = (float)sqrt(tpl_var * iv);
        if (a < 20) {
            s1 += ys1[(long)(492 + a) * 105 + t] - ys1[(long)a * 105 + t];
            s2 += ys2[(long)(492 + a) * 105 + t] - ys2[(long)a * 105 + t];
        }
    }
}

// ---------------------------------------------------------------------------
// K5: pack h = (img - mu_i) + i*(tpl - mu_t) and forward DIF FFT along z
__global__ __launch_bounds__(256) void k_pack_fft_z(const float* __restrict__ img,
                                                    const float* __restrict__ tpl,
                                                    double2* __restrict__ d,
                                                    const double* __restrict__ stats) {
    int line = blockIdx.x * blockDim.x + threadIdx.x;
    long b = (long)line << 5;
    const double mu_i = stats[3], mu_t = stats[4];
    double2 a[32];
    const float4* pi4 = (const float4*)(img + b);
    const float4* pt4 = (const float4*)(tpl + b);
#pragma unroll
    for (int q = 0; q < 8; ++q) {
        float4 fi = pi4[q];
        float4 ft = pt4[q];
        a[q * 4 + 0] = make_double2((double)fi.x - mu_i, (double)ft.x - mu_t);
        a[q * 4 + 1] = make_double2((double)fi.y - mu_i, (double)ft.y - mu_t);
        a[q * 4 + 2] = make_double2((double)fi.z - mu_i, (double)ft.z - mu_t);
        a[q * 4 + 3] = make_double2((double)fi.w - mu_i, (double)ft.w - mu_t);
    }
    fft32<0>(a);
#pragma unroll
    for (int z = 0; z < 32; ++z) d[b + z] = a[z];
}

// ---------------------------------------------------------------------------
// K6/K7/K9/K10: length-512 line FFT via LDS. 4 lines per block (batched over z).
// INV=0: DIF forward (natural->bitrev). INV=1: DIT inverse (bitrev->natural).
template <int INV>
__global__ __launch_bounds__(256) void k_fft_lines512(double2* __restrict__ d,
                                                      int line_stride, int outer_stride) {
    __shared__ double re[4][516];
    __shared__ double im[4][516];
    __shared__ double twc[256];
    __shared__ double tws[256];
    const int tid = threadIdx.x;
    const int bx = blockIdx.x;
    const int outer = bx >> 3, zt = bx & 7;
    const long base = (long)outer * outer_stride + zt * 4;

    {
        double sv, cv;
        sincos(2.0 * 3.14159265358979323846 * (double)tid / 512.0, &sv, &cv);
        twc[tid] = cv;
        tws[tid] = INV ? sv : -sv;
    }

#pragma unroll
    for (int i = 0; i < 8; ++i) {
        int idx = tid + 256 * i;
        int y = idx >> 2, c = idx & 3;
        double2 v = d[base + (long)y * line_stride + c];
        re[c][y] = v.x;
        im[c][y] = v.y;
    }
    __syncthreads();

    const int c = tid >> 6, lane = tid & 63;
    if (INV == 0) {
        int mul = 1;
        for (int h = 256; h >= 1; h >>= 1, mul <<= 1) {
#pragma unroll
            for (int i = 0; i < 4; ++i) {
                int j = lane + (i << 6);
                int t = j & (h - 1);
                int i0 = ((j & ~(h - 1)) << 1) + t;
                int i1 = i0 + h;
                double ur = re[c][i0], ui = im[c][i0];
                double vr = re[c][i1], vi = im[c][i1];
                re[c][i0] = ur + vr;
                im[c][i0] = ui + vi;
                double dr = ur - vr, di = ui - vi;
                double wc = twc[t * mul], ws = tws[t * mul];
                re[c][i1] = dr * wc - di * ws;
                im[c][i1] = dr * ws + di * wc;
            }
            __syncthreads();
        }
    } else {
        int mul = 256;
        for (int h = 1; h <= 256; h <<= 1, mul >>= 1) {
#pragma unroll
            for (int i = 0; i < 4; ++i) {
                int j = lane + (i << 6);
                int t = j & (h - 1);
                int i0 = ((j & ~(h - 1)) << 1) + t;
                int i1 = i0 + h;
                double wc = twc[t * mul], ws = tws[t * mul];
                double vr = re[c][i1], vi = im[c][i1];
                double wr = vr * wc - vi * ws;
                double wi = vr * ws + vi * wc;
                double ur = re[c][i0], ui = im[c][i0];
                re[c][i0] = ur + wr;
                im[c][i0] = ui + wi;
                re[c][i1] = ur - wr;
                im[c][i1] = ui - wi;
            }
            __syncthreads();
        }
    }

#pragma unroll
    for (int i = 0; i < 8; ++i) {
        int idx = tid + 256 * i;
        int y = idx >> 2, cc = idx & 3;
        d[base + (long)y * line_stride + cc] = make_double2(re[cc][y], im[cc][y]);
    }
}

// ---------------------------------------------------------------------------
// K8: cross-power: split packed spectrum H = F + iG, form P = F*conj(G), P(-k)=conj(P(k))
__global__ __launch_bounds__(256) void k_crosspow(double2* __restrict__ d) {
    int idx = blockIdx.x * blockDim.x + threadIdx.x;
    int x = idx >> 14, y = (idx >> 5) & 511, z = idx & 31;
    int mx = mir_br(x), my = mir_br(y), mz = mir_br(z);
    int midx = ((mx << 9 | my) << 5) | mz;
    if (idx > midx) return;
    double2 h1 = d[idx], h2 = d[midx];
    double Fr = 0.5 * (h1.x + h2.x), Fi = 0.5 * (h1.y - h2.y);
    double Gr = 0.5 * (h1.y + h2.y), Gi = 0.5 * (h2.x - h1.x);
    double Pr = Fr * Gr + Fi * Gi;
    double Pi = Fi * Gr - Fr * Gi;
    d[idx] = make_double2(Pr, Pi);
    d[midx] = make_double2(Pr, -Pi);
}

// ---------------------------------------------------------------------------
// K11: inverse DIT FFT along z, |.|/N, roll by (256,256,16), write rolled_cc
__global__ __launch_bounds__(256) void k_invz_abs_roll(const double2* __restrict__ d,
                                                       float* __restrict__ out) {
    int line = blockIdx.x * blockDim.x + threadIdx.x;
    int x = line >> 9, y = line & 511;
    long b = (long)line << 5;
    double2 a[32];
#pragma unroll
    for (int z = 0; z < 32; ++z) a[z] = d[b + z];
    fft32<1>(a);
    const double invN = 1.0 / (double)NTOT;
    int xo = (x + 256) & 511, yo = (y + 256) & 511;
    long ob = OUT_ROLL_OFF + ((long)(xo << 9 | yo) << 5);
#pragma unroll
    for (int z = 0; z < 32; ++z) {
        int zo = (z + 16) & 31;
        out[ob + zo] = (float)(sqrt(a[z].x * a[z].x + a[z].y * a[z].y) * invN);
    }
}

// ---------------------------------------------------------------------------
// K12: ncc = rolled_cc slice / denominator, NaN -> 0
__global__ __launch_bounds__(256) void k_ncc(const float* __restrict__ denom,
                                             float* __restrict__ out) {
    int i = blockIdx.x * blockDim.x + threadIdx.x;
    if (i >= 2205) return;
    int a = i / 105, r = i % 105;
    int bq = r / 5, cq = r % 5;
    long ridx = OUT_ROLL_OFF + ((long)((246 + a) * 512 + (246 + bq)) << 5) + (14 + cq);
    float v = out[ridx] / denom[i];
    if (isnan(v)) v = 0.f;
    out[OUT_NCC_OFF + i] = v;
}

// K13: argmax over ncc (first-max) + log-Gaussian subpixel refine -> sh_x/y/z
__global__ __launch_bounds__(256) void k_argmax_refine(float* __restrict__ out) {
    const float* ncc = out + OUT_NCC_OFF;
    __shared__ float bv[256];
    __shared__ int bi[256];
    float best = -INFINITY;
    int bidx = 0x7fffffff;
    for (int i = threadIdx.x; i < 2205; i += 256) {
        float v = ncc[i];
        if (v > best) { best = v; bidx = i; }
    }
    bv[threadIdx.x] = best;
    bi[threadIdx.x] = bidx;
    __syncthreads();
    for (int s = 128; s > 0; s >>= 1) {
        if (threadIdx.x < s) {
            if (bv[threadIdx.x + s] > bv[threadIdx.x] ||
                (bv[threadIdx.x + s] == bv[threadIdx.x] && bi[threadIdx.x + s] < bi[threadIdx.x])) {
                bv[threadIdx.x] = bv[threadIdx.x + s];
                bi[threadIdx.x] = bi[threadIdx.x + s];
            }
        }
        __syncthreads();
    }
    if (threadIdx.x == 0) {
        int idx = bi[0];
        int sx = idx / 105, sy = (idx % 105) / 5, sz = idx % 5;
        auto cl = [](int v, int n) { return v < 0 ? 0 : (v >= n ? n - 1 : v); };
        auto V = [&](int dx, int dy, int dz) {
            return logf(ncc[cl(sx + dx, 21) * 105 + cl(sy + dy, 21) * 5 + cl(sz + dz, 5)]);
        };
        float v0 = V(0, 0, 0);
        float six = 6.0f * v0;
        float am = V(-1, 0, 0), ap = V(1, 0, 0);
        float bm = V(0, -1, 0), bp = V(0, 1, 0);
        float cm = V(0, 0, -1), cp = V(0, 0, 1);
        out[0] = (float)(-(sx - 10)) - (am - ap) / (2.f * am - six + 2.f * ap);
        out[1] = (float)(-(sy - 10)) - (bm - bp) / (2.f * bm - six + 2.f * bp);
        out[2] = (float)(-(sz - 2)) - (cm - cp) / (2.f * cm - six + 2.f * cp);
    }
}

// ---------------------------------------------------------------------------
extern "C" void kernel_launch(void* const* d_in, const int* in_sizes, int n_in,
                              void* d_out, int out_size, void* d_ws, size_t ws_size,
                              hipStream_t stream) {
    const float* fr = (const float*)d_in[0];
    const float* tpl = (const float*)d_in[1];
    float* out = (float*)d_out;
    char* ws = (char*)d_ws;

    double2* Hc = (double2*)(ws + WS_HC_OFF);
    double* zs1 = (double*)(ws + WS_ZS1_OFF);
    double* zs2 = (double*)(ws + WS_ZS2_OFF);
    double* ys1 = (double*)(ws + WS_YS1_OFF);
    double* ys2 = (double*)(ws + WS_YS2_OFF);
    double* stats = (double*)(ws + WS_STATS_OFF);
    float* denom = (float*)(ws + WS_DENOM_OFF);

    hipMemsetAsync(stats, 0, 8 * sizeof(double), stream);

    k_reduce_stats<<<1024, 256, 0, stream>>>(fr, tpl, stats);
    k_finalize_stats<<<1, 1, 0, stream>>>(stats);

    // windowed means (use raw img) - run before Hc is written (buffers overlap Hc)
    k_winz<<<NLINES / 256, 256, 0, stream>>>(fr, zs1, zs2);
    k_winy<<<10, 256, 0, stream>>>(zs1, zs2, ys1, ys2);
    k_winx_denom<<<1, 128, 0, stream>>>(ys1, ys2, stats, denom);

    // forward FFT (packed real pair), z then y then x
    k_pack_fft_z<<<NLINES / 256, 256, 0, stream>>>(fr, tpl, Hc, stats);
    k_fft_lines512<0><<<4096, 256, 0, stream>>>(Hc, /*line_stride=*/32, /*outer_stride=*/16384);  // y
    k_fft_lines512<0><<<4096, 256, 0, stream>>>(Hc, /*line_stride=*/16384, /*outer_stride=*/32);  // x

    // cross-power spectrum
    k_crosspow<<<NTOT / 256, 256, 0, stream>>>(Hc);

    // inverse FFT: x, y, then z fused with abs+roll+output
    k_fft_lines512<1><<<4096, 256, 0, stream>>>(Hc, /*line_stride=*/16384, /*outer_stride=*/32);  // x
    k_fft_lines512<1><<<4096, 256, 0, stream>>>(Hc, /*line_stride=*/32, /*outer_stride=*/16384);  // y
    k_invz_abs_roll<<<NLINES / 256, 256, 0, stream>>>(Hc, out);

    // ncc + argmax/subpixel
    k_ncc<<<9, 256, 0, stream>>>(denom, out);
    k_argmax_refine<<<1, 256, 0, stream>>>(out);
}

// Round 3
// 528.216 us; speedup vs baseline: 1.2411x; 1.2411x over previous
//
#include <hip/hip_runtime.h>
#include <hip/hip_bf16.h>
#include <math.h>

// ---------------------------------------------------------------------------
// MotionCorrect: FFT-based NCC on 512x512x32 volume (fp64 FFT path).
//   out = [sh_x, sh_y, sh_z, rolled_cc(512*512*32), ncc(21*21*5)]
// ---------------------------------------------------------------------------

#define NTOT 8388608            // 512*512*32
#define NLINES 262144           // 512*512
#define OUT_ROLL_OFF 3
#define OUT_NCC_OFF 8388611     // 3 + NTOT
#define WIN_PROD 6777792.0      // 492*492*28
#define EPSV 1e-8

// ws layout (bytes)
#define WS_HC_OFF 0UL                       // double2[NTOT] = 134217728 B
#define WS_ZS1_OFF 0UL                      // overlaps Hc (consumed before Hc written)
#define WS_ZS2_OFF 10485760UL
#define WS_YS1_OFF 20971520UL
#define WS_YS2_OFF 21401600UL
#define WS_STATS_OFF 134217728UL            // double[8]
#define WS_DENOM_OFF 134217792UL            // float[2205]

typedef double2 cplx;
__device__ __forceinline__ cplx cadd(cplx a, cplx b){ return make_double2(a.x+b.x, a.y+b.y); }
__device__ __forceinline__ cplx csub(cplx a, cplx b){ return make_double2(a.x-b.x, a.y-b.y); }
__device__ __forceinline__ cplx cmul(cplx a, cplx b){ return make_double2(a.x*b.x-a.y*b.y, a.x*b.y+a.y*b.x); }
__device__ __forceinline__ cplx cnegi(cplx a){ return make_double2(a.y, -a.x); }   // a * (-i)
__device__ __forceinline__ cplx cposi(cplx a){ return make_double2(-a.y, a.x); }   // a * (+i)

#define RT2 0.70710678118654752440
// forward eighth-turns: e^{-i pi/4}, e^{-i 3pi/4}
__device__ __forceinline__ cplx cw64f(cplx v){ return make_double2(RT2*(v.x+v.y), RT2*(v.y-v.x)); }
__device__ __forceinline__ cplx cw192f(cplx v){ return make_double2(RT2*(v.y-v.x), -RT2*(v.x+v.y)); }
// inverse eighth-turns: e^{+i pi/4}, e^{+i 3pi/4}
__device__ __forceinline__ cplx cw64i(cplx v){ return make_double2(RT2*(v.x-v.y), RT2*(v.x+v.y)); }
__device__ __forceinline__ cplx cw192i(cplx v){ return make_double2(-RT2*(v.x+v.y), RT2*(v.x-v.y)); }

// Skewed LDS layout: one pad double between consecutive 8-blocks.
// addr(i) = i + (i>>3). 8-blocks stay contiguous (block k starts at 9k);
// block-start bank-pairs 9k mod 16 are bijective; all strided radix-4 passes
// land at exactly 4 lanes/bank-pair (the b64 wave64 floor).
#define SKW(i) ((i) + ((i) >> 3))
#define LROW 580                 // >= SKW(511)=574; row phase = 8*row banks

__device__ __forceinline__ cplx ldsld(const double* re, const double* im, int i){
    int p = SKW(i);
    return make_double2(re[p], im[p]);
}
__device__ __forceinline__ void ldsst(double* re, double* im, int i, cplx v){
    int p = SKW(i);
    re[p] = v.x; im[p] = v.y;
}

// ---------------------------------------------------------------------------
// Radix-4 LDS pass: forward covers DIF stages (2H, H); twiddle tables hold
// forward sign (twc=cos, tws=-sin).
template <int H>
__device__ __forceinline__ void fwd_r4(double* re, double* im,
                                       const double* twc, const double* tws, int lane) {
    const int MUL2 = 256 / (2 * H);
#pragma unroll
    for (int g = 0; g < 2; ++g) {
        int j = lane + 64 * g;                    // 0..127
        int t = j & (H - 1);
        int i0 = ((j & ~(H - 1)) << 2) + t;
        cplx A = ldsld(re, im, i0);
        cplx B = ldsld(re, im, i0 + H);
        cplx C = ldsld(re, im, i0 + 2 * H);
        cplx D = ldsld(re, im, i0 + 3 * H);
        double wc = twc[t * MUL2], ws = tws[t * MUL2];
        cplx w1 = make_double2(wc, ws);
        cplx w2 = make_double2(wc * wc - ws * ws, 2.0 * wc * ws);   // w1^2
        cplx u = cadd(A, C), v = cadd(B, D);
        cplx p = cmul(csub(A, C), w1);
        cplx q = cnegi(cmul(csub(B, D), w1));     // W^{(t+H)*MUL2} = -i*w1
        ldsst(re, im, i0,         cadd(u, v));
        ldsst(re, im, i0 + H,     cmul(csub(u, v), w2));
        ldsst(re, im, i0 + 2 * H, cadd(p, q));
        ldsst(re, im, i0 + 3 * H, cmul(csub(p, q), w2));
    }
}

// inverse covers DIT stages (H, 2H) with conjugate twiddles
template <int H>
__device__ __forceinline__ void inv_r4(double* re, double* im,
                                       const double* twc, const double* tws, int lane) {
    const int MUL2 = 256 / (2 * H);
#pragma unroll
    for (int g = 0; g < 2; ++g) {
        int j = lane + 64 * g;
        int t = j & (H - 1);
        int i0 = ((j & ~(H - 1)) << 2) + t;
        cplx A = ldsld(re, im, i0);
        cplx B = ldsld(re, im, i0 + H);
        cplx C = ldsld(re, im, i0 + 2 * H);
        cplx D = ldsld(re, im, i0 + 3 * H);
        double wc = twc[t * MUL2], ws = -tws[t * MUL2];             // conj
        cplx w2 = make_double2(wc, ws);
        cplx wH = make_double2(wc * wc - ws * ws, 2.0 * wc * ws);   // stage-H twiddle
        cplx vb = cmul(B, wH), vd = cmul(D, wH);
        cplx a0 = cadd(A, vb), a1 = csub(A, vb);
        cplx c0 = cadd(C, vd), c1 = csub(C, vd);
        cplx t0 = cmul(c0, w2);
        cplx t1 = cposi(cmul(c1, w2));            // W^{+(t+H)*MUL2} = +i*w2
        ldsst(re, im, i0,         cadd(a0, t0));
        ldsst(re, im, i0 + 2 * H, csub(a0, t0));
        ldsst(re, im, i0 + H,     cadd(a1, t1));
        ldsst(re, im, i0 + 3 * H, csub(a1, t1));
    }
}

// ---------------------------------------------------------------------------
// Register radix-8 tail: forward DIF stages h=4,2,1 on contiguous 8-blocks.
// Skew keeps block k contiguous at [9k, 9k+8); scalar indexing (odd blocks are
// not 16B-aligned, so no double2 casts).
__device__ __forceinline__ void fwd_r8(double* re, double* im, int lane) {
    double* rp = re + 9 * lane;
    double* ip = im + 9 * lane;
    cplx L0 = make_double2(rp[0], ip[0]), L1 = make_double2(rp[1], ip[1]);
    cplx L2 = make_double2(rp[2], ip[2]), L3 = make_double2(rp[3], ip[3]);
    cplx L4 = make_double2(rp[4], ip[4]), L5 = make_double2(rp[5], ip[5]);
    cplx L6 = make_double2(rp[6], ip[6]), L7 = make_double2(rp[7], ip[7]);
    // stage h=4: twiddles W^{64r} = {1, e^{-i pi/4}, -i, e^{-i 3pi/4}}
    cplx s0 = cadd(L0, L4), d0 = csub(L0, L4);
    cplx s1 = cadd(L1, L5), d1 = cw64f(csub(L1, L5));
    cplx s2 = cadd(L2, L6), d2 = cnegi(csub(L2, L6));
    cplx s3 = cadd(L3, L7), d3 = cw192f(csub(L3, L7));
    // stage h=2: {1, -i}
    cplx e0 = cadd(s0, s2), e2 = csub(s0, s2);
    cplx e1 = cadd(s1, s3), e3 = cnegi(csub(s1, s3));
    cplx f0 = cadd(d0, d2), f2 = csub(d0, d2);
    cplx f1 = cadd(d1, d3), f3 = cnegi(csub(d1, d3));
    // stage h=1: plain
    cplx o0 = cadd(e0, e1), o1 = csub(e0, e1), o2 = cadd(e2, e3), o3 = csub(e2, e3);
    cplx o4 = cadd(f0, f1), o5 = csub(f0, f1), o6 = cadd(f2, f3), o7 = csub(f2, f3);
    rp[0] = o0.x; ip[0] = o0.y;  rp[1] = o1.x; ip[1] = o1.y;
    rp[2] = o2.x; ip[2] = o2.y;  rp[3] = o3.x; ip[3] = o3.y;
    rp[4] = o4.x; ip[4] = o4.y;  rp[5] = o5.x; ip[5] = o5.y;
    rp[6] = o6.x; ip[6] = o6.y;  rp[7] = o7.x; ip[7] = o7.y;
}

// inverse DIT stages h=1,2,4 (conjugate twiddles)
__device__ __forceinline__ void inv_r8(double* re, double* im, int lane) {
    double* rp = re + 9 * lane;
    double* ip = im + 9 * lane;
    cplx L0 = make_double2(rp[0], ip[0]), L1 = make_double2(rp[1], ip[1]);
    cplx L2 = make_double2(rp[2], ip[2]), L3 = make_double2(rp[3], ip[3]);
    cplx L4 = make_double2(rp[4], ip[4]), L5 = make_double2(rp[5], ip[5]);
    cplx L6 = make_double2(rp[6], ip[6]), L7 = make_double2(rp[7], ip[7]);
    // h=1
    cplx a0 = cadd(L0, L1), a1 = csub(L0, L1), a2 = cadd(L2, L3), a3 = csub(L2, L3);
    cplx a4 = cadd(L4, L5), a5 = csub(L4, L5), a6 = cadd(L6, L7), a7 = csub(L6, L7);
    // h=2: {1, +i}
    cplx b0 = cadd(a0, a2), b2 = csub(a0, a2);
    cplx v13 = cposi(a3);
    cplx b1 = cadd(a1, v13), b3 = csub(a1, v13);
    cplx b4 = cadd(a4, a6), b6 = csub(a4, a6);
    cplx v57 = cposi(a7);
    cplx b5 = cadd(a5, v57), b7 = csub(a5, v57);
    // h=4: W^{+64r} = {1, e^{+i pi/4}, +i, e^{+i 3pi/4}}
    cplx v0 = b4, v1 = cw64i(b5), v2 = cposi(b6), v3 = cw192i(b7);
    cplx o0 = cadd(b0, v0), o4 = csub(b0, v0);
    cplx o1 = cadd(b1, v1), o5 = csub(b1, v1);
    cplx o2 = cadd(b2, v2), o6 = csub(b2, v2);
    cplx o3 = cadd(b3, v3), o7 = csub(b3, v3);
    rp[0] = o0.x; ip[0] = o0.y;  rp[1] = o1.x; ip[1] = o1.y;
    rp[2] = o2.x; ip[2] = o2.y;  rp[3] = o3.x; ip[3] = o3.y;
    rp[4] = o4.x; ip[4] = o4.y;  rp[5] = o5.x; ip[5] = o5.y;
    rp[6] = o6.x; ip[6] = o6.y;  rp[7] = o7.x; ip[7] = o7.y;
}

// full 512-point line FFT: one wave per line -> no s_barrier between passes;
// wave_barrier pins compiler ordering of cross-lane LDS dependencies.
template <int INV>
__device__ __forceinline__ void line_fft512(double* re, double* im,
                                            const double* twc, const double* tws, int lane) {
    if (!INV) {
        fwd_r4<128>(re, im, twc, tws, lane);   // stages 256,128
        __builtin_amdgcn_wave_barrier();
        fwd_r4<32>(re, im, twc, tws, lane);    // 64,32
        __builtin_amdgcn_wave_barrier();
        fwd_r4<8>(re, im, twc, tws, lane);     // 16,8
        __builtin_amdgcn_wave_barrier();
        fwd_r8(re, im, lane);                  // 4,2,1
    } else {
        inv_r8(re, im, lane);                  // 1,2,4
        __builtin_amdgcn_wave_barrier();
        inv_r4<8>(re, im, twc, tws, lane);     // 8,16
        __builtin_amdgcn_wave_barrier();
        inv_r4<32>(re, im, twc, tws, lane);    // 32,64
        __builtin_amdgcn_wave_barrier();
        inv_r4<128>(re, im, twc, tws, lane);   // 128,256
    }
}

// ---------------------------------------------------------------------------
// per-thread radix-2 FFT of length 32 (z-axis), fully unrolled (bench-verified)
static constexpr double W32C_[16] = {
    1.0, 0.98078528040323044913, 0.92387953251128675613, 0.83146961230254523708,
    0.70710678118654752440, 0.55557023301960222474, 0.38268343236508977173, 0.19509032201612826785,
    0.0, -0.19509032201612826785, -0.38268343236508977173, -0.55557023301960222474,
    -0.70710678118654752440, -0.83146961230254523708, -0.92387953251128675613, -0.98078528040323044913};
static constexpr double W32S_[16] = {
    0.0, 0.19509032201612826785, 0.38268343236508977173, 0.55557023301960222474,
    0.70710678118654752440, 0.83146961230254523708, 0.92387953251128675613, 0.98078528040323044913,
    1.0, 0.98078528040323044913, 0.92387953251128675613, 0.83146961230254523708,
    0.70710678118654752440, 0.55557023301960222474, 0.38268343236508977173, 0.19509032201612826785};

template <int INV>
__device__ __forceinline__ void fft32(double2* a) {
    if (INV == 0) {
#pragma unroll
        for (int s = 0; s < 5; ++s) {
            const int h = 16 >> s;
#pragma unroll
            for (int j = 0; j < 16; ++j) {
                const int t = j & (h - 1);
                const int i0 = ((j >> (4 - s)) << (5 - s)) + t;
                const int i1 = i0 + h;
                double2 u = a[i0], v = a[i1];
                a[i0] = make_double2(u.x + v.x, u.y + v.y);
                double dx = u.x - v.x, dy = u.y - v.y;
                const double wc = W32C_[t << s];
                const double ws = -W32S_[t << s];
                a[i1] = make_double2(dx * wc - dy * ws, dx * ws + dy * wc);
            }
        }
    } else {
#pragma unroll
        for (int s = 0; s < 5; ++s) {
            const int h = 1 << s;
#pragma unroll
            for (int j = 0; j < 16; ++j) {
                const int t = j & (h - 1);
                const int i0 = ((j >> s) << (s + 1)) + t;
                const int i1 = i0 + h;
                const double wc = W32C_[t << (4 - s)];
                const double ws = W32S_[t << (4 - s)];
                double2 u = a[i0], vr = a[i1];
                double2 v = make_double2(vr.x * wc - vr.y * ws, vr.x * ws + vr.y * wc);
                a[i0] = make_double2(u.x + v.x, u.y + v.y);
                a[i1] = make_double2(u.x - v.x, u.y - v.y);
            }
        }
    }
}

// bit-reversed-storage mirror of frequency negation (involution), any 2^k size
__device__ __forceinline__ int mir_br(int b) {
    if (b == 0) return 0;
    int s = 31 - __clz(b);
    return (3 << s) - 1 - b;
}

// ---------------------------------------------------------------------------
// K1: global sums: sum(img), sum(tpl), sum(tpl^2)
__global__ __launch_bounds__(256) void k_reduce_stats(const float4* __restrict__ img4,
                                                      const float4* __restrict__ tpl4,
                                                      double* __restrict__ stats) {
    double si = 0, st = 0, st2 = 0;
    const int stride = gridDim.x * blockDim.x;
    for (int i = blockIdx.x * blockDim.x + threadIdx.x; i < NTOT / 4; i += stride) {
        float4 a = img4[i];
        si += (double)a.x + (double)a.y + (double)a.z + (double)a.w;
        float4 t = tpl4[i];
        double t0 = t.x, t1 = t.y, t2 = t.z, t3 = t.w;
        st += t0 + t1 + t2 + t3;
        st2 += t0 * t0 + t1 * t1 + t2 * t2 + t3 * t3;
    }
    __shared__ double s0[256], s1[256], s2[256];
    int tid = threadIdx.x;
    s0[tid] = si; s1[tid] = st; s2[tid] = st2;
    __syncthreads();
    for (int s = 128; s > 0; s >>= 1) {
        if (tid < s) {
            s0[tid] += s0[tid + s];
            s1[tid] += s1[tid + s];
            s2[tid] += s2[tid + s];
        }
        __syncthreads();
    }
    if (tid == 0) {
        atomicAdd(&stats[0], s0[0]);
        atomicAdd(&stats[1], s1[0]);
        atomicAdd(&stats[2], s2[0]);
    }
}

__global__ void k_finalize_stats(double* stats) {
    double mu_i = stats[0] / (double)NTOT;
    double mu_t = stats[1] / (double)NTOT;
    stats[3] = mu_i;
    stats[4] = mu_t;
    stats[5] = stats[2] - (double)NTOT * mu_t * mu_t + EPSV;  // tpl_var
}

// ---------------------------------------------------------------------------
// K2: z-direction sliding-window sums (window 28 of 32 -> 5) for img and img^2
__global__ __launch_bounds__(256) void k_winz(const float* __restrict__ img,
                                              double* __restrict__ zs1,
                                              double* __restrict__ zs2) {
    int line = blockIdx.x * blockDim.x + threadIdx.x;
    long b = (long)line << 5;
    float v[32];
    const float4* p4 = (const float4*)(img + b);
#pragma unroll
    for (int q = 0; q < 8; ++q) {
        float4 f = p4[q];
        v[q * 4 + 0] = f.x; v[q * 4 + 1] = f.y; v[q * 4 + 2] = f.z; v[q * 4 + 3] = f.w;
    }
    double s1 = 0, s2 = 0;
#pragma unroll
    for (int z = 0; z < 28; ++z) {
        double t = (double)v[z];
        s1 += t;
        s2 += t * t;
    }
    long ob = (long)line * 5;
    zs1[ob] = s1; zs2[ob] = s2;
#pragma unroll
    for (int k = 1; k <= 4; ++k) {
        double a = (double)v[27 + k], r = (double)v[k - 1];
        s1 += a - r;
        s2 += a * a - r * r;
        zs1[ob + k] = s1; zs2[ob + k] = s2;
    }
}

// K3: y-direction sliding window (492 of 512 -> 21)
__global__ __launch_bounds__(256) void k_winy(const double* __restrict__ zs1,
                                              const double* __restrict__ zs2,
                                              double* __restrict__ ys1,
                                              double* __restrict__ ys2) {
    int t = blockIdx.x * blockDim.x + threadIdx.x;
    if (t >= 2560) return;
    int x = t / 5, c = t % 5;
    long base = (long)x * 512 * 5 + c;
    double s1 = 0, s2 = 0;
    for (int y = 0; y < 492; ++y) {
        s1 += zs1[base + (long)y * 5];
        s2 += zs2[base + (long)y * 5];
    }
    long ob = (long)x * 105 + c;
    ys1[ob] = s1; ys2[ob] = s2;
    for (int k = 1; k <= 20; ++k) {
        s1 += zs1[base + (long)(491 + k) * 5] - zs1[base + (long)(k - 1) * 5];
        s2 += zs2[base + (long)(491 + k) * 5] - zs2[base + (long)(k - 1) * 5];
        ys1[ob + (long)k * 5] = s1;
        ys2[ob + (long)k * 5] = s2;
    }
}

// K4: x-direction sliding window (492 of 512 -> 21) + denominator
__global__ __launch_bounds__(128) void k_winx_denom(const double* __restrict__ ys1,
                                                    const double* __restrict__ ys2,
                                                    const double* __restrict__ stats,
                                                    float* __restrict__ denom) {
    int t = blockIdx.x * blockDim.x + threadIdx.x;
    if (t >= 105) return;
    double tpl_var = stats[5];
    double s1 = 0, s2 = 0;
    for (int x = 0; x < 492; ++x) {
        s1 += ys1[(long)x * 105 + t];
        s2 += ys2[(long)x * 105 + t];
    }
    const double wm = 1.0 / WIN_PROD;
    for (int a = 0; a < 21; ++a) {
        double m1 = s1 * wm, m2 = s2 * wm;
        double iv = m2 - (m1 * m1) / (double)NTOT + EPSV;
        if (iv < 0) iv = 0;
        denom[a * 105 + t] = (float)sqrt(tpl_var * iv);
        if (a < 20) {
            s1 += ys1[(long)(492 + a) * 105 + t] - ys1[(long)a * 105 + t];
            s2 += ys2[(long)(492 + a) * 105 + t] - ys2[(long)a * 105 + t];
        }
    }
}

// ---------------------------------------------------------------------------
// K5: pack h = (img - mu_i) + i*(tpl - mu_t), forward DIF FFT along z
__global__ __launch_bounds__(256) void k_pack_fft_z(const float* __restrict__ img,
                                                    const float* __restrict__ tpl,
                                                    double2* __restrict__ d,
                                                    const double* __restrict__ stats) {
    int line = blockIdx.x * blockDim.x + threadIdx.x;
    long b = (long)line << 5;
    const double mu_i = stats[3], mu_t = stats[4];
    double2 a[32];
    const float4* pi4 = (const float4*)(img + b);
    const float4* pt4 = (const float4*)(tpl + b);
#pragma unroll
    for (int q = 0; q < 8; ++q) {
        float4 fi = pi4[q];
        float4 ft = pt4[q];
        a[q * 4 + 0] = make_double2((double)fi.x - mu_i, (double)ft.x - mu_t);
        a[q * 4 + 1] = make_double2((double)fi.y - mu_i, (double)ft.y - mu_t);
        a[q * 4 + 2] = make_double2((double)fi.z - mu_i, (double)ft.z - mu_t);
        a[q * 4 + 3] = make_double2((double)fi.w - mu_i, (double)ft.w - mu_t);
    }
    fft32<0>(a);
#pragma unroll
    for (int z = 0; z < 32; ++z) d[b + z] = a[z];
}

// ---------------------------------------------------------------------------
// K6/K8: y-direction 512-point line FFT. 8 lines (8 consecutive z) per block,
// one wave per line; barriers only around the LDS load/store phases.
template <int INV>
__global__ __launch_bounds__(512, 4) void k_fft8(double2* __restrict__ d) {
    __shared__ double lre[8][LROW];
    __shared__ double lim[8][LROW];
    __shared__ double twc[256], tws[256];
    const int tid = threadIdx.x;
    if (tid < 256) {
        double sv, cv;
        sincos(6.283185307179586476925286766559 * (double)tid / 512.0, &sv, &cv);
        twc[tid] = cv;
        tws[tid] = -sv;           // forward sign; inverse conjugates at use
    }
    const long base = (long)(blockIdx.x >> 2) * 16384 + (long)(blockIdx.x & 3) * 8;
#pragma unroll
    for (int i = 0; i < 8; ++i) {
        int idx = tid + 512 * i;
        int lz = idx & 7, e = idx >> 3;           // 128B contiguous per 8 lanes
        double2 v = d[base + (long)e * 32 + lz];
        lre[lz][SKW(e)] = v.x;
        lim[lz][SKW(e)] = v.y;
    }
    __syncthreads();
    const int c = tid >> 6, lane = tid & 63;
    line_fft512<INV>(lre[c], lim[c], twc, tws, lane);
    __syncthreads();
#pragma unroll
    for (int i = 0; i < 8; ++i) {
        int idx = tid + 512 * i;
        int lz = idx & 7, e = idx >> 3;
        int p = SKW(e);
        d[base + (long)e * 32 + lz] = make_double2(lre[lz][p], lim[lz][p]);
    }
}

// ---------------------------------------------------------------------------
// K7: fused forward-x-FFT + cross-power + inverse-x-FFT.
// Block pairs line-group A=(y, ztA: 4 z's) with its frequency-mirror group
// B=(mir_br(y), ztB). x-mirror is local (bitrev order); y/z mirror via pairing.
__global__ __launch_bounds__(512, 4) void k_fftx_cross(double2* __restrict__ d) {
    const int bid = blockIdx.x;
    const int y = bid >> 3, ztA = bid & 7;
    const int my = mir_br(y);
    const int ztB = (0x45672310 >> (ztA * 4)) & 15;   // 3-bit mir_br table {0,1,3,2,7,6,5,4}
    const int keyA = (y << 3) | ztA, keyB = (my << 3) | ztB;
    if (keyA > keyB) return;                          // canonical pair only
    const bool dup = (keyA == keyB);

    __shared__ double lre[8][LROW];
    __shared__ double lim[8][LROW];
    __shared__ double twc[256], tws[256];
    const int tid = threadIdx.x;
    if (tid < 256) {
        double sv, cv;
        sincos(6.283185307179586476925286766559 * (double)tid / 512.0, &sv, &cv);
        twc[tid] = cv;
        tws[tid] = -sv;
    }
    const int baseA = y * 32 + ztA * 4;
    const int baseB = my * 32 + ztB * 4;
#pragma unroll
    for (int i = 0; i < 8; ++i) {
        int idx = tid + 512 * i;
        int a = idx & 3, half = (idx >> 2) & 1, bx = idx >> 3;
        int l = half * 4 + a;
        double2 v = d[(long)bx * 16384 + (half ? baseB : baseA) + a];
        lre[l][SKW(bx)] = v.x;
        lim[l][SKW(bx)] = v.y;
    }
    __syncthreads();
    const int c = tid >> 6, lane = tid & 63;
    line_fft512<0>(lre[c], lim[c], twc, tws, lane);
    __syncthreads();
    // cross-power: split packed spectrum H = F + iG, P = F*conj(G), P(-k)=conj(P(k)).
    // Sources are rows 0..3 only; partners written into rows 4..7 -> no intra-phase race.
#pragma unroll
    for (int i = 0; i < 4; ++i) {
        int p = tid + 512 * i;                    // 0..2047
        int a = p >> 9, bx = p & 511;
        int am = (ztA == 0) ? (a ^ (a >> 1)) : (3 - a);   // z-line mirror within pair
        int mbx = mir_br(bx);
        int p1 = SKW(bx), p2 = SKW(mbx);
        double h1r = lre[a][p1], h1i = lim[a][p1];
        double h2r = lre[4 + am][p2], h2i = lim[4 + am][p2];
        double Fr = 0.5 * (h1r + h2r), Fi = 0.5 * (h1i - h2i);
        double Gr = 0.5 * (h1i + h2i), Gi = 0.5 * (h2r - h1r);
        double Pr = Fr * Gr + Fi * Gi;
        double Pi = Fi * Gr - Fr * Gi;
        lre[a][p1] = Pr;      lim[a][p1] = Pi;
        lre[4 + am][p2] = Pr; lim[4 + am][p2] = -Pi;
    }
    __syncthreads();
    line_fft512<1>(lre[c], lim[c], twc, tws, lane);
    __syncthreads();
#pragma unroll
    for (int i = 0; i < 8; ++i) {
        int idx = tid + 512 * i;
        int a = idx & 3, half = (idx >> 2) & 1, bx = idx >> 3;
        if (dup && half) continue;                // self-paired: skip duplicate stores
        int l = half * 4 + a;
        int p = SKW(bx);
        d[(long)bx * 16384 + (half ? baseB : baseA) + a] = make_double2(lre[l][p], lim[l][p]);
    }
}

// ---------------------------------------------------------------------------
// K9: inverse DIT FFT along z, |.|/N, roll by (256,256,16), write rolled_cc
__global__ __launch_bounds__(256) void k_invz_abs_roll(const double2* __restrict__ d,
                                                       float* __restrict__ out) {
    int line = blockIdx.x * blockDim.x + threadIdx.x;
    int x = line >> 9, y = line & 511;
    long b = (long)line << 5;
    double2 a[32];
#pragma unroll
    for (int z = 0; z < 32; ++z) a[z] = d[b + z];
    fft32<1>(a);
    const double invN = 1.0 / (double)NTOT;
    int xo = (x + 256) & 511, yo = (y + 256) & 511;
    long ob = OUT_ROLL_OFF + ((long)(xo << 9 | yo) << 5);
    // z-roll keeps 4-alignment (16 mod 4 == 0) -> float4 stores
#pragma unroll
    for (int q = 0; q < 8; ++q) {
        int z = q * 4;
        int zo = (z + 16) & 31;
        float4 w;
        w.x = (float)(sqrt(a[z + 0].x * a[z + 0].x + a[z + 0].y * a[z + 0].y) * invN);
        w.y = (float)(sqrt(a[z + 1].x * a[z + 1].x + a[z + 1].y * a[z + 1].y) * invN);
        w.z = (float)(sqrt(a[z + 2].x * a[z + 2].x + a[z + 2].y * a[z + 2].y) * invN);
        w.w = (float)(sqrt(a[z + 3].x * a[z + 3].x + a[z + 3].y * a[z + 3].y) * invN);
        *(float4*)(out + ob + zo) = w;
    }
}

// ---------------------------------------------------------------------------
// K10: ncc = rolled_cc slice / denominator, NaN -> 0
__global__ __launch_bounds__(256) void k_ncc(const float* __restrict__ denom,
                                             float* __restrict__ out) {
    int i = blockIdx.x * blockDim.x + threadIdx.x;
    if (i >= 2205) return;
    int a = i / 105, r = i % 105;
    int bq = r / 5, cq = r % 5;
    long ridx = OUT_ROLL_OFF + ((long)((246 + a) * 512 + (246 + bq)) << 5) + (14 + cq);
    float v = out[ridx] / denom[i];
    if (isnan(v)) v = 0.f;
    out[OUT_NCC_OFF + i] = v;
}

// K11: argmax over ncc (first-max) + log-Gaussian subpixel refine -> sh_x/y/z
__global__ __launch_bounds__(256) void k_argmax_refine(float* __restrict__ out) {
    const float* ncc = out + OUT_NCC_OFF;
    __shared__ float bv[256];
    __shared__ int bi[256];
    float best = -INFINITY;
    int bidx = 0x7fffffff;
    for (int i = threadIdx.x; i < 2205; i += 256) {
        float v = ncc[i];
        if (v > best) { best = v; bidx = i; }
    }
    bv[threadIdx.x] = best;
    bi[threadIdx.x] = bidx;
    __syncthreads();
    for (int s = 128; s > 0; s >>= 1) {
        if (threadIdx.x < s) {
            if (bv[threadIdx.x + s] > bv[threadIdx.x] ||
                (bv[threadIdx.x + s] == bv[threadIdx.x] && bi[threadIdx.x + s] < bi[threadIdx.x])) {
                bv[threadIdx.x] = bv[threadIdx.x + s];
                bi[threadIdx.x] = bi[threadIdx.x + s];
            }
        }
        __syncthreads();
    }
    if (threadIdx.x == 0) {
        int idx = bi[0];
        int sx = idx / 105, sy = (idx % 105) / 5, sz = idx % 5;
        auto cl = [](int v, int n) { return v < 0 ? 0 : (v >= n ? n - 1 : v); };
        auto V = [&](int dx, int dy, int dz) {
            return logf(ncc[cl(sx + dx, 21) * 105 + cl(sy + dy, 21) * 5 + cl(sz + dz, 5)]);
        };
        float v0 = V(0, 0, 0);
        float six = 6.0f * v0;
        float am = V(-1, 0, 0), ap = V(1, 0, 0);
        float bm = V(0, -1, 0), bp = V(0, 1, 0);
        float cm = V(0, 0, -1), cp = V(0, 0, 1);
        out[0] = (float)(-(sx - 10)) - (am - ap) / (2.f * am - six + 2.f * ap);
        out[1] = (float)(-(sy - 10)) - (bm - bp) / (2.f * bm - six + 2.f * bp);
        out[2] = (float)(-(sz - 2)) - (cm - cp) / (2.f * cm - six + 2.f * cp);
    }
}

// ---------------------------------------------------------------------------
extern "C" void kernel_launch(void* const* d_in, const int* in_sizes, int n_in,
                              void* d_out, int out_size, void* d_ws, size_t ws_size,
                              hipStream_t stream) {
    const float* fr = (const float*)d_in[0];
    const float* tpl = (const float*)d_in[1];
    float* out = (float*)d_out;
    char* ws = (char*)d_ws;

    double2* Hc = (double2*)(ws + WS_HC_OFF);
    double* zs1 = (double*)(ws + WS_ZS1_OFF);
    double* zs2 = (double*)(ws + WS_ZS2_OFF);
    double* ys1 = (double*)(ws + WS_YS1_OFF);
    double* ys2 = (double*)(ws + WS_YS2_OFF);
    double* stats = (double*)(ws + WS_STATS_OFF);
    float* denom = (float*)(ws + WS_DENOM_OFF);

    hipMemsetAsync(stats, 0, 8 * sizeof(double), stream);

    k_reduce_stats<<<2048, 256, 0, stream>>>((const float4*)fr, (const float4*)tpl, stats);
    k_finalize_stats<<<1, 1, 0, stream>>>(stats);

    // windowed means (raw img) - consumed into denom before Hc overwrites buffers
    k_winz<<<NLINES / 256, 256, 0, stream>>>(fr, zs1, zs2);
    k_winy<<<10, 256, 0, stream>>>(zs1, zs2, ys1, ys2);
    k_winx_denom<<<1, 128, 0, stream>>>(ys1, ys2, stats, denom);

    // forward: pack + z-FFT, then y-FFT
    k_pack_fft_z<<<NLINES / 256, 256, 0, stream>>>(fr, tpl, Hc, stats);
    k_fft8<0><<<2048, 512, 0, stream>>>(Hc);

    // fused fwd-x-FFT + cross-power + inv-x-FFT
    k_fftx_cross<<<4096, 512, 0, stream>>>(Hc);

    // inverse: y-FFT, then z-FFT fused with abs+roll+output
    k_fft8<1><<<2048, 512, 0, stream>>>(Hc);
    k_invz_abs_roll<<<NLINES / 256, 256, 0, stream>>>(Hc, out);

    // ncc + argmax/subpixel
    k_ncc<<<9, 256, 0, stream>>>(denom, out);
    k_argmax_refine<<<1, 256, 0, stream>>>(out);
}

// Round 4
// 472.419 us; speedup vs baseline: 1.3877x; 1.1181x over previous
//
#include <hip/hip_runtime.h>
#include <hip/hip_bf16.h>
#include <math.h>

// ---------------------------------------------------------------------------
// MotionCorrect: FFT-based NCC on 512x512x32 volume (fp64 FFT path).
//   out = [sh_x, sh_y, sh_z, rolled_cc(512*512*32), ncc(21*21*5)]
// ---------------------------------------------------------------------------

#define NTOT 8388608            // 512*512*32
#define NLINES 262144           // 512*512
#define OUT_ROLL_OFF 3
#define OUT_NCC_OFF 8388611     // 3 + NTOT
#define WIN_PROD 6777792.0      // 492*492*28
#define EPSV 1e-8

// ws layout (bytes)
#define WS_HC_OFF 0UL                       // double2[NTOT] = 134217728 B
#define WS_ZS1_OFF 0UL                      // overlaps Hc (consumed before Hc written)
#define WS_ZS2_OFF 10485760UL
#define WS_YS1_OFF 20971520UL
#define WS_YS2_OFF 21401600UL
#define WS_PART_OFF 31457280UL              // double2[1024] partials (consumed pre-pack)
#define WS_DENOM_OFF 134217728UL            // float[2205] (outside Hc; proven ws range)

typedef double2 cplx;
__device__ __forceinline__ cplx cadd(cplx a, cplx b){ return make_double2(a.x+b.x, a.y+b.y); }
__device__ __forceinline__ cplx csub(cplx a, cplx b){ return make_double2(a.x-b.x, a.y-b.y); }
__device__ __forceinline__ cplx cmul(cplx a, cplx b){ return make_double2(a.x*b.x-a.y*b.y, a.x*b.y+a.y*b.x); }
__device__ __forceinline__ cplx cnegi(cplx a){ return make_double2(a.y, -a.x); }   // a * (-i)
__device__ __forceinline__ cplx cposi(cplx a){ return make_double2(-a.y, a.x); }   // a * (+i)

#define RT2 0.70710678118654752440
// forward eighth-turns: e^{-i pi/4}, e^{-i 3pi/4}
__device__ __forceinline__ cplx cw64f(cplx v){ return make_double2(RT2*(v.x+v.y), RT2*(v.y-v.x)); }
__device__ __forceinline__ cplx cw192f(cplx v){ return make_double2(RT2*(v.y-v.x), -RT2*(v.x+v.y)); }
// inverse eighth-turns: e^{+i pi/4}, e^{+i 3pi/4}
__device__ __forceinline__ cplx cw64i(cplx v){ return make_double2(RT2*(v.x-v.y), RT2*(v.x+v.y)); }
__device__ __forceinline__ cplx cw192i(cplx v){ return make_double2(-RT2*(v.x+v.y), RT2*(v.x-v.y)); }

// Skewed LDS layout: one pad double between consecutive 8-blocks.
// addr(i) = i + (i>>3). 8-blocks stay contiguous (block k starts at 9k);
// block-start bank-pairs 9k mod 16 are bijective; all strided radix-4 passes
// land at exactly 4 lanes/bank-pair (the b64 wave64 floor).
#define SKW(i) ((i) + ((i) >> 3))
#define LROW 580                 // >= SKW(511)=574; row phase = 8*row banks

__device__ __forceinline__ cplx ldsld(const double* re, const double* im, int i){
    int p = SKW(i);
    return make_double2(re[p], im[p]);
}
__device__ __forceinline__ void ldsst(double* re, double* im, int i, cplx v){
    int p = SKW(i);
    re[p] = v.x; im[p] = v.y;
}

// ---------------------------------------------------------------------------
// Radix-4 LDS pass: forward covers DIF stages (2H, H); twiddle tables hold
// forward sign (twc=cos, tws=-sin).
template <int H>
__device__ __forceinline__ void fwd_r4(double* re, double* im,
                                       const double* twc, const double* tws, int lane) {
    const int MUL2 = 256 / (2 * H);
#pragma unroll
    for (int g = 0; g < 2; ++g) {
        int j = lane + 64 * g;                    // 0..127
        int t = j & (H - 1);
        int i0 = ((j & ~(H - 1)) << 2) + t;
        cplx A = ldsld(re, im, i0);
        cplx B = ldsld(re, im, i0 + H);
        cplx C = ldsld(re, im, i0 + 2 * H);
        cplx D = ldsld(re, im, i0 + 3 * H);
        double wc = twc[t * MUL2], ws = tws[t * MUL2];
        cplx w1 = make_double2(wc, ws);
        cplx w2 = make_double2(wc * wc - ws * ws, 2.0 * wc * ws);   // w1^2
        cplx u = cadd(A, C), v = cadd(B, D);
        cplx p = cmul(csub(A, C), w1);
        cplx q = cnegi(cmul(csub(B, D), w1));     // W^{(t+H)*MUL2} = -i*w1
        ldsst(re, im, i0,         cadd(u, v));
        ldsst(re, im, i0 + H,     cmul(csub(u, v), w2));
        ldsst(re, im, i0 + 2 * H, cadd(p, q));
        ldsst(re, im, i0 + 3 * H, cmul(csub(p, q), w2));
    }
}

// inverse covers DIT stages (H, 2H) with conjugate twiddles
template <int H>
__device__ __forceinline__ void inv_r4(double* re, double* im,
                                       const double* twc, const double* tws, int lane) {
    const int MUL2 = 256 / (2 * H);
#pragma unroll
    for (int g = 0; g < 2; ++g) {
        int j = lane + 64 * g;
        int t = j & (H - 1);
        int i0 = ((j & ~(H - 1)) << 2) + t;
        cplx A = ldsld(re, im, i0);
        cplx B = ldsld(re, im, i0 + H);
        cplx C = ldsld(re, im, i0 + 2 * H);
        cplx D = ldsld(re, im, i0 + 3 * H);
        double wc = twc[t * MUL2], ws = -tws[t * MUL2];             // conj
        cplx w2 = make_double2(wc, ws);
        cplx wH = make_double2(wc * wc - ws * ws, 2.0 * wc * ws);   // stage-H twiddle
        cplx vb = cmul(B, wH), vd = cmul(D, wH);
        cplx a0 = cadd(A, vb), a1 = csub(A, vb);
        cplx c0 = cadd(C, vd), c1 = csub(C, vd);
        cplx t0 = cmul(c0, w2);
        cplx t1 = cposi(cmul(c1, w2));            // W^{+(t+H)*MUL2} = +i*w2
        ldsst(re, im, i0,         cadd(a0, t0));
        ldsst(re, im, i0 + 2 * H, csub(a0, t0));
        ldsst(re, im, i0 + H,     cadd(a1, t1));
        ldsst(re, im, i0 + 3 * H, csub(a1, t1));
    }
}

// ---------------------------------------------------------------------------
// Register radix-8 tail: forward DIF stages h=4,2,1 on contiguous 8-blocks.
// Skew keeps block k contiguous at [9k, 9k+8); scalar indexing (odd blocks are
// not 16B-aligned, so no double2 casts).
__device__ __forceinline__ void fwd_r8(double* re, double* im, int lane) {
    double* rp = re + 9 * lane;
    double* ip = im + 9 * lane;
    cplx L0 = make_double2(rp[0], ip[0]), L1 = make_double2(rp[1], ip[1]);
    cplx L2 = make_double2(rp[2], ip[2]), L3 = make_double2(rp[3], ip[3]);
    cplx L4 = make_double2(rp[4], ip[4]), L5 = make_double2(rp[5], ip[5]);
    cplx L6 = make_double2(rp[6], ip[6]), L7 = make_double2(rp[7], ip[7]);
    // stage h=4: twiddles W^{64r} = {1, e^{-i pi/4}, -i, e^{-i 3pi/4}}
    cplx s0 = cadd(L0, L4), d0 = csub(L0, L4);
    cplx s1 = cadd(L1, L5), d1 = cw64f(csub(L1, L5));
    cplx s2 = cadd(L2, L6), d2 = cnegi(csub(L2, L6));
    cplx s3 = cadd(L3, L7), d3 = cw192f(csub(L3, L7));
    // stage h=2: {1, -i}
    cplx e0 = cadd(s0, s2), e2 = csub(s0, s2);
    cplx e1 = cadd(s1, s3), e3 = cnegi(csub(s1, s3));
    cplx f0 = cadd(d0, d2), f2 = csub(d0, d2);
    cplx f1 = cadd(d1, d3), f3 = cnegi(csub(d1, d3));
    // stage h=1: plain
    cplx o0 = cadd(e0, e1), o1 = csub(e0, e1), o2 = cadd(e2, e3), o3 = csub(e2, e3);
    cplx o4 = cadd(f0, f1), o5 = csub(f0, f1), o6 = cadd(f2, f3), o7 = csub(f2, f3);
    rp[0] = o0.x; ip[0] = o0.y;  rp[1] = o1.x; ip[1] = o1.y;
    rp[2] = o2.x; ip[2] = o2.y;  rp[3] = o3.x; ip[3] = o3.y;
    rp[4] = o4.x; ip[4] = o4.y;  rp[5] = o5.x; ip[5] = o5.y;
    rp[6] = o6.x; ip[6] = o6.y;  rp[7] = o7.x; ip[7] = o7.y;
}

// inverse DIT stages h=1,2,4 (conjugate twiddles)
__device__ __forceinline__ void inv_r8(double* re, double* im, int lane) {
    double* rp = re + 9 * lane;
    double* ip = im + 9 * lane;
    cplx L0 = make_double2(rp[0], ip[0]), L1 = make_double2(rp[1], ip[1]);
    cplx L2 = make_double2(rp[2], ip[2]), L3 = make_double2(rp[3], ip[3]);
    cplx L4 = make_double2(rp[4], ip[4]), L5 = make_double2(rp[5], ip[5]);
    cplx L6 = make_double2(rp[6], ip[6]), L7 = make_double2(rp[7], ip[7]);
    // h=1
    cplx a0 = cadd(L0, L1), a1 = csub(L0, L1), a2 = cadd(L2, L3), a3 = csub(L2, L3);
    cplx a4 = cadd(L4, L5), a5 = csub(L4, L5), a6 = cadd(L6, L7), a7 = csub(L6, L7);
    // h=2: {1, +i}
    cplx b0 = cadd(a0, a2), b2 = csub(a0, a2);
    cplx v13 = cposi(a3);
    cplx b1 = cadd(a1, v13), b3 = csub(a1, v13);
    cplx b4 = cadd(a4, a6), b6 = csub(a4, a6);
    cplx v57 = cposi(a7);
    cplx b5 = cadd(a5, v57), b7 = csub(a5, v57);
    // h=4: W^{+64r} = {1, e^{+i pi/4}, +i, e^{+i 3pi/4}}
    cplx v0 = b4, v1 = cw64i(b5), v2 = cposi(b6), v3 = cw192i(b7);
    cplx o0 = cadd(b0, v0), o4 = csub(b0, v0);
    cplx o1 = cadd(b1, v1), o5 = csub(b1, v1);
    cplx o2 = cadd(b2, v2), o6 = csub(b2, v2);
    cplx o3 = cadd(b3, v3), o7 = csub(b3, v3);
    rp[0] = o0.x; ip[0] = o0.y;  rp[1] = o1.x; ip[1] = o1.y;
    rp[2] = o2.x; ip[2] = o2.y;  rp[3] = o3.x; ip[3] = o3.y;
    rp[4] = o4.x; ip[4] = o4.y;  rp[5] = o5.x; ip[5] = o5.y;
    rp[6] = o6.x; ip[6] = o6.y;  rp[7] = o7.x; ip[7] = o7.y;
}

// full 512-point line FFT: one wave per line -> no s_barrier between passes;
// wave_barrier pins compiler ordering of cross-lane LDS dependencies.
template <int INV>
__device__ __forceinline__ void line_fft512(double* re, double* im,
                                            const double* twc, const double* tws, int lane) {
    if (!INV) {
        fwd_r4<128>(re, im, twc, tws, lane);   // stages 256,128
        __builtin_amdgcn_wave_barrier();
        fwd_r4<32>(re, im, twc, tws, lane);    // 64,32
        __builtin_amdgcn_wave_barrier();
        fwd_r4<8>(re, im, twc, tws, lane);     // 16,8
        __builtin_amdgcn_wave_barrier();
        fwd_r8(re, im, lane);                  // 4,2,1
    } else {
        inv_r8(re, im, lane);                  // 1,2,4
        __builtin_amdgcn_wave_barrier();
        inv_r4<8>(re, im, twc, tws, lane);     // 8,16
        __builtin_amdgcn_wave_barrier();
        inv_r4<32>(re, im, twc, tws, lane);    // 32,64
        __builtin_amdgcn_wave_barrier();
        inv_r4<128>(re, im, twc, tws, lane);   // 128,256
    }
}

// ---------------------------------------------------------------------------
// per-thread radix-2 FFT of length 32 (z-axis), fully unrolled (bench-verified)
static constexpr double W32C_[16] = {
    1.0, 0.98078528040323044913, 0.92387953251128675613, 0.83146961230254523708,
    0.70710678118654752440, 0.55557023301960222474, 0.38268343236508977173, 0.19509032201612826785,
    0.0, -0.19509032201612826785, -0.38268343236508977173, -0.55557023301960222474,
    -0.70710678118654752440, -0.83146961230254523708, -0.92387953251128675613, -0.98078528040323044913};
static constexpr double W32S_[16] = {
    0.0, 0.19509032201612826785, 0.38268343236508977173, 0.55557023301960222474,
    0.70710678118654752440, 0.83146961230254523708, 0.92387953251128675613, 0.98078528040323044913,
    1.0, 0.98078528040323044913, 0.92387953251128675613, 0.83146961230254523708,
    0.70710678118654752440, 0.55557023301960222474, 0.38268343236508977173, 0.19509032201612826785};

template <int INV>
__device__ __forceinline__ void fft32(double2* a) {
    if (INV == 0) {
#pragma unroll
        for (int s = 0; s < 5; ++s) {
            const int h = 16 >> s;
#pragma unroll
            for (int j = 0; j < 16; ++j) {
                const int t = j & (h - 1);
                const int i0 = ((j >> (4 - s)) << (5 - s)) + t;
                const int i1 = i0 + h;
                double2 u = a[i0], v = a[i1];
                a[i0] = make_double2(u.x + v.x, u.y + v.y);
                double dx = u.x - v.x, dy = u.y - v.y;
                const double wc = W32C_[t << s];
                const double ws = -W32S_[t << s];
                a[i1] = make_double2(dx * wc - dy * ws, dx * ws + dy * wc);
            }
        }
    } else {
#pragma unroll
        for (int s = 0; s < 5; ++s) {
            const int h = 1 << s;
#pragma unroll
            for (int j = 0; j < 16; ++j) {
                const int t = j & (h - 1);
                const int i0 = ((j >> s) << (s + 1)) + t;
                const int i1 = i0 + h;
                const double wc = W32C_[t << (4 - s)];
                const double ws = W32S_[t << (4 - s)];
                double2 u = a[i0], vr = a[i1];
                double2 v = make_double2(vr.x * wc - vr.y * ws, vr.x * ws + vr.y * wc);
                a[i0] = make_double2(u.x + v.x, u.y + v.y);
                a[i1] = make_double2(u.x - v.x, u.y - v.y);
            }
        }
    }
}

// bit-reversed-storage mirror of frequency negation (involution), any 2^k size
__device__ __forceinline__ int mir_br(int b) {
    if (b == 0) return 0;
    int s = 31 - __clz(b);
    return (3 << s) - 1 - b;
}

// ---------------------------------------------------------------------------
// K1: template sums -> per-block partials (NO atomics; fp64 same-address
// atomicAdd serialization cost 91us in round 3)
__global__ __launch_bounds__(256) void k_reduce_tpl(const float4* __restrict__ tpl4,
                                                    double2* __restrict__ part) {
    double st = 0, st2 = 0;
    const int stride = gridDim.x * blockDim.x;
    for (int i = blockIdx.x * blockDim.x + threadIdx.x; i < NTOT / 4; i += stride) {
        float4 t = tpl4[i];
        double t0 = t.x, t1 = t.y, t2 = t.z, t3 = t.w;
        st += t0 + t1 + t2 + t3;
        st2 += t0 * t0 + t1 * t1 + t2 * t2 + t3 * t3;
    }
    __shared__ double s1[256], s2[256];
    int tid = threadIdx.x;
    s1[tid] = st; s2[tid] = st2;
    __syncthreads();
    for (int s = 128; s > 0; s >>= 1) {
        if (tid < s) { s1[tid] += s1[tid + s]; s2[tid] += s2[tid + s]; }
        __syncthreads();
    }
    if (tid == 0) part[blockIdx.x] = make_double2(s1[0], s2[0]);
}

// ---------------------------------------------------------------------------
// K2: z-direction sliding-window sums (window 28 of 32 -> 5) for img and img^2
__global__ __launch_bounds__(256) void k_winz(const float* __restrict__ img,
                                              double* __restrict__ zs1,
                                              double* __restrict__ zs2) {
    int line = blockIdx.x * blockDim.x + threadIdx.x;
    long b = (long)line << 5;
    float v[32];
    const float4* p4 = (const float4*)(img + b);
#pragma unroll
    for (int q = 0; q < 8; ++q) {
        float4 f = p4[q];
        v[q * 4 + 0] = f.x; v[q * 4 + 1] = f.y; v[q * 4 + 2] = f.z; v[q * 4 + 3] = f.w;
    }
    double s1 = 0, s2 = 0;
#pragma unroll
    for (int z = 0; z < 28; ++z) {
        double t = (double)v[z];
        s1 += t;
        s2 += t * t;
    }
    long ob = (long)line * 5;
    zs1[ob] = s1; zs2[ob] = s2;
#pragma unroll
    for (int k = 1; k <= 4; ++k) {
        double a = (double)v[27 + k], r = (double)v[k - 1];
        s1 += a - r;
        s2 += a * a - r * r;
        zs1[ob + k] = s1; zs2[ob + k] = s2;
    }
}

// K3: y-direction sliding window (492 of 512 -> 21)
__global__ __launch_bounds__(256) void k_winy(const double* __restrict__ zs1,
                                              const double* __restrict__ zs2,
                                              double* __restrict__ ys1,
                                              double* __restrict__ ys2) {
    int t = blockIdx.x * blockDim.x + threadIdx.x;
    if (t >= 2560) return;
    int x = t / 5, c = t % 5;
    long base = (long)x * 512 * 5 + c;
    double s1 = 0, s2 = 0;
    for (int y = 0; y < 492; ++y) {
        s1 += zs1[base + (long)y * 5];
        s2 += zs2[base + (long)y * 5];
    }
    long ob = (long)x * 105 + c;
    ys1[ob] = s1; ys2[ob] = s2;
    for (int k = 1; k <= 20; ++k) {
        s1 += zs1[base + (long)(491 + k) * 5] - zs1[base + (long)(k - 1) * 5];
        s2 += zs2[base + (long)(491 + k) * 5] - zs2[base + (long)(k - 1) * 5];
        ys1[ob + (long)k * 5] = s1;
        ys2[ob + (long)k * 5] = s2;
    }
}

// K4: reduce tpl partials -> tpl_var, then x-direction sliding window + denom
__global__ __launch_bounds__(256) void k_winx_denom(const double* __restrict__ ys1,
                                                    const double* __restrict__ ys2,
                                                    const double2* __restrict__ part,
                                                    float* __restrict__ denom) {
    __shared__ double s1s[256], s2s[256];
    __shared__ double tplvar_s;
    int tid = threadIdx.x;
    {
        double a1 = 0, a2 = 0;
#pragma unroll
        for (int q = 0; q < 4; ++q) {
            double2 p = part[tid + 256 * q];
            a1 += p.x; a2 += p.y;
        }
        s1s[tid] = a1; s2s[tid] = a2;
        __syncthreads();
        for (int s = 128; s > 0; s >>= 1) {
            if (tid < s) { s1s[tid] += s1s[tid + s]; s2s[tid] += s2s[tid + s]; }
            __syncthreads();
        }
        if (tid == 0) {
            double S1 = s1s[0], S2 = s2s[0];
            double mu = S1 / (double)NTOT;
            tplvar_s = S2 - (double)NTOT * mu * mu + EPSV;
        }
        __syncthreads();
    }
    if (tid >= 105) return;
    const double tpl_var = tplvar_s;
    double s1 = 0, s2 = 0;
    for (int x = 0; x < 492; ++x) {
        s1 += ys1[(long)x * 105 + tid];
        s2 += ys2[(long)x * 105 + tid];
    }
    const double wm = 1.0 / WIN_PROD;
    for (int a = 0; a < 21; ++a) {
        double m1 = s1 * wm, m2 = s2 * wm;
        double iv = m2 - (m1 * m1) / (double)NTOT + EPSV;
        if (iv < 0) iv = 0;
        denom[a * 105 + tid] = (float)sqrt(tpl_var * iv);
        if (a < 20) {
            s1 += ys1[(long)(492 + a) * 105 + tid] - ys1[(long)a * 105 + tid];
            s2 += ys2[(long)(492 + a) * 105 + tid] - ys2[(long)a * 105 + tid];
        }
    }
}

// ---------------------------------------------------------------------------
// K5: pack h = img + i*tpl (RAW; mean subtraction deferred to DC-bin zeroing:
// FFT of zero-mean data has DC bin exactly 0), forward DIF FFT along z
__global__ __launch_bounds__(256) void k_pack_fft_z(const float* __restrict__ img,
                                                    const float* __restrict__ tpl,
                                                    double2* __restrict__ d) {
    int line = blockIdx.x * blockDim.x + threadIdx.x;
    long b = (long)line << 5;
    double2 a[32];
    const float4* pi4 = (const float4*)(img + b);
    const float4* pt4 = (const float4*)(tpl + b);
#pragma unroll
    for (int q = 0; q < 8; ++q) {
        float4 fi = pi4[q];
        float4 ft = pt4[q];
        a[q * 4 + 0] = make_double2((double)fi.x, (double)ft.x);
        a[q * 4 + 1] = make_double2((double)fi.y, (double)ft.y);
        a[q * 4 + 2] = make_double2((double)fi.z, (double)ft.z);
        a[q * 4 + 3] = make_double2((double)fi.w, (double)ft.w);
    }
    fft32<0>(a);
#pragma unroll
    for (int z = 0; z < 32; ++z) d[b + z] = a[z];
}

// ---------------------------------------------------------------------------
// K6/K8: y-direction 512-point line FFT. 8 lines (8 consecutive z) per block,
// one wave per line; barriers only around the LDS load/store phases.
template <int INV>
__global__ __launch_bounds__(512, 4) void k_fft8(double2* __restrict__ d) {
    __shared__ double lre[8][LROW];
    __shared__ double lim[8][LROW];
    __shared__ double twc[256], tws[256];
    const int tid = threadIdx.x;
    if (tid < 256) {
        double sv, cv;
        sincos(6.283185307179586476925286766559 * (double)tid / 512.0, &sv, &cv);
        twc[tid] = cv;
        tws[tid] = -sv;           // forward sign; inverse conjugates at use
    }
    const long base = (long)(blockIdx.x >> 2) * 16384 + (long)(blockIdx.x & 3) * 8;
#pragma unroll
    for (int i = 0; i < 8; ++i) {
        int idx = tid + 512 * i;
        int lz = idx & 7, e = idx >> 3;           // 128B contiguous per 8 lanes
        double2 v = d[base + (long)e * 32 + lz];
        lre[lz][SKW(e)] = v.x;
        lim[lz][SKW(e)] = v.y;
    }
    __syncthreads();
    const int c = tid >> 6, lane = tid & 63;
    line_fft512<INV>(lre[c], lim[c], twc, tws, lane);
    __syncthreads();
#pragma unroll
    for (int i = 0; i < 8; ++i) {
        int idx = tid + 512 * i;
        int lz = idx & 7, e = idx >> 3;
        int p = SKW(e);
        d[base + (long)e * 32 + lz] = make_double2(lre[lz][p], lim[lz][p]);
    }
}

// ---------------------------------------------------------------------------
// K7: fused forward-x-FFT + cross-power + inverse-x-FFT.
// Block pairs line-group A=(y, ztA: 4 z's) with its frequency-mirror group
// B=(mir_br(y), ztB). x-mirror is local (bitrev order); y/z mirror via pairing.
__global__ __launch_bounds__(512, 4) void k_fftx_cross(double2* __restrict__ d) {
    const int bid = blockIdx.x;
    const int y = bid >> 3, ztA = bid & 7;
    const int my = mir_br(y);
    const int ztB = (0x45672310 >> (ztA * 4)) & 15;   // 3-bit mir_br table {0,1,3,2,7,6,5,4}
    const int keyA = (y << 3) | ztA, keyB = (my << 3) | ztB;
    if (keyA > keyB) return;                          // canonical pair only
    const bool dup = (keyA == keyB);

    __shared__ double lre[8][LROW];
    __shared__ double lim[8][LROW];
    __shared__ double twc[256], tws[256];
    const int tid = threadIdx.x;
    if (tid < 256) {
        double sv, cv;
        sincos(6.283185307179586476925286766559 * (double)tid / 512.0, &sv, &cv);
        twc[tid] = cv;
        tws[tid] = -sv;
    }
    const int baseA = y * 32 + ztA * 4;
    const int baseB = my * 32 + ztB * 4;
#pragma unroll
    for (int i = 0; i < 8; ++i) {
        int idx = tid + 512 * i;
        int a = idx & 3, half = (idx >> 2) & 1, bx = idx >> 3;
        int l = half * 4 + a;
        double2 v = d[(long)bx * 16384 + (half ? baseB : baseA) + a];
        lre[l][SKW(bx)] = v.x;
        lim[l][SKW(bx)] = v.y;
    }
    __syncthreads();
    const int c = tid >> 6, lane = tid & 63;
    line_fft512<0>(lre[c], lim[c], twc, tws, lane);
    __syncthreads();
    // cross-power: split packed spectrum H = F + iG, P = F*conj(G), P(-k)=conj(P(k)).
    // Sources are rows 0..3 only; partners written into rows 4..7 -> no intra-phase race.
    // DC bin (block 0, p==0): zero-mean data => H(0,0,0) = 0 => P = 0. Both copies
    // (row 0 and its dup in row 4) are owned solely by the p==0 thread.
    const bool dcblk = (bid == 0);
#pragma unroll
    for (int i = 0; i < 4; ++i) {
        int p = tid + 512 * i;                    // 0..2047
        int a = p >> 9, bx = p & 511;
        int am = (ztA == 0) ? (a ^ (a >> 1)) : (3 - a);   // z-line mirror within pair
        int mbx = mir_br(bx);
        int p1 = SKW(bx), p2 = SKW(mbx);
        if (dcblk && p == 0) {
            lre[0][0] = 0.0; lim[0][0] = 0.0;
            lre[4][0] = 0.0; lim[4][0] = 0.0;
            continue;
        }
        double h1r = lre[a][p1], h1i = lim[a][p1];
        double h2r = lre[4 + am][p2], h2i = lim[4 + am][p2];
        double Fr = 0.5 * (h1r + h2r), Fi = 0.5 * (h1i - h2i);
        double Gr = 0.5 * (h1i + h2i), Gi = 0.5 * (h2r - h1r);
        double Pr = Fr * Gr + Fi * Gi;
        double Pi = Fi * Gr - Fr * Gi;
        lre[a][p1] = Pr;      lim[a][p1] = Pi;
        lre[4 + am][p2] = Pr; lim[4 + am][p2] = -Pi;
    }
    __syncthreads();
    line_fft512<1>(lre[c], lim[c], twc, tws, lane);
    __syncthreads();
#pragma unroll
    for (int i = 0; i < 8; ++i) {
        int idx = tid + 512 * i;
        int a = idx & 3, half = (idx >> 2) & 1, bx = idx >> 3;
        if (dup && half) continue;                // self-paired: skip duplicate stores
        int l = half * 4 + a;
        int p = SKW(bx);
        d[(long)bx * 16384 + (half ? baseB : baseA) + a] = make_double2(lre[l][p], lim[l][p]);
    }
}

// ---------------------------------------------------------------------------
// K9: inverse DIT FFT along z, |.|/N, roll by (256,256,16), write rolled_cc
__global__ __launch_bounds__(256) void k_invz_abs_roll(const double2* __restrict__ d,
                                                       float* __restrict__ out) {
    int line = blockIdx.x * blockDim.x + threadIdx.x;
    int x = line >> 9, y = line & 511;
    long b = (long)line << 5;
    double2 a[32];
#pragma unroll
    for (int z = 0; z < 32; ++z) a[z] = d[b + z];
    fft32<1>(a);
    const double invN = 1.0 / (double)NTOT;
    int xo = (x + 256) & 511, yo = (y + 256) & 511;
    long ob = OUT_ROLL_OFF + ((long)(xo << 9 | yo) << 5);
    // z-roll keeps 4-alignment (16 mod 4 == 0) -> float4 stores
#pragma unroll
    for (int q = 0; q < 8; ++q) {
        int z = q * 4;
        int zo = (z + 16) & 31;
        float4 w;
        w.x = (float)(sqrt(a[z + 0].x * a[z + 0].x + a[z + 0].y * a[z + 0].y) * invN);
        w.y = (float)(sqrt(a[z + 1].x * a[z + 1].x + a[z + 1].y * a[z + 1].y) * invN);
        w.z = (float)(sqrt(a[z + 2].x * a[z + 2].x + a[z + 2].y * a[z + 2].y) * invN);
        w.w = (float)(sqrt(a[z + 3].x * a[z + 3].x + a[z + 3].y * a[z + 3].y) * invN);
        *(float4*)(out + ob + zo) = w;
    }
}

// ---------------------------------------------------------------------------
// K10: fused ncc + argmax (first-max) + log-Gaussian subpixel refine
__global__ __launch_bounds__(256) void k_ncc_argmax(const float* __restrict__ denom,
                                                    float* __restrict__ out) {
    __shared__ float sncc[2205];
    __shared__ float bv[256];
    __shared__ int bi[256];
    const int tid = threadIdx.x;
    float best = -INFINITY;
    int bidx = 0x7fffffff;
    for (int i = tid; i < 2205; i += 256) {
        int a = i / 105, r = i % 105;
        int bq = r / 5, cq = r % 5;
        long ridx = OUT_ROLL_OFF + ((long)((246 + a) * 512 + (246 + bq)) << 5) + (14 + cq);
        float v = out[ridx] / denom[i];
        if (isnan(v)) v = 0.f;
        out[OUT_NCC_OFF + i] = v;
        sncc[i] = v;
        if (v > best) { best = v; bidx = i; }
    }
    bv[tid] = best;
    bi[tid] = bidx;
    __syncthreads();
    for (int s = 128; s > 0; s >>= 1) {
        if (tid < s) {
            if (bv[tid + s] > bv[tid] || (bv[tid + s] == bv[tid] && bi[tid + s] < bi[tid])) {
                bv[tid] = bv[tid + s];
                bi[tid] = bi[tid + s];
            }
        }
        __syncthreads();
    }
    if (tid == 0) {
        int idx = bi[0];
        int sx = idx / 105, sy = (idx % 105) / 5, sz = idx % 5;
        auto cl = [](int v, int n) { return v < 0 ? 0 : (v >= n ? n - 1 : v); };
        auto V = [&](int dx, int dy, int dz) {
            return logf(sncc[cl(sx + dx, 21) * 105 + cl(sy + dy, 21) * 5 + cl(sz + dz, 5)]);
        };
        float v0 = V(0, 0, 0);
        float six = 6.0f * v0;
        float am = V(-1, 0, 0), ap = V(1, 0, 0);
        float bm = V(0, -1, 0), bp = V(0, 1, 0);
        float cm = V(0, 0, -1), cp = V(0, 0, 1);
        out[0] = (float)(-(sx - 10)) - (am - ap) / (2.f * am - six + 2.f * ap);
        out[1] = (float)(-(sy - 10)) - (bm - bp) / (2.f * bm - six + 2.f * bp);
        out[2] = (float)(-(sz - 2)) - (cm - cp) / (2.f * cm - six + 2.f * cp);
    }
}

// ---------------------------------------------------------------------------
extern "C" void kernel_launch(void* const* d_in, const int* in_sizes, int n_in,
                              void* d_out, int out_size, void* d_ws, size_t ws_size,
                              hipStream_t stream) {
    const float* fr = (const float*)d_in[0];
    const float* tpl = (const float*)d_in[1];
    float* out = (float*)d_out;
    char* ws = (char*)d_ws;

    double2* Hc = (double2*)(ws + WS_HC_OFF);
    double* zs1 = (double*)(ws + WS_ZS1_OFF);
    double* zs2 = (double*)(ws + WS_ZS2_OFF);
    double* ys1 = (double*)(ws + WS_YS1_OFF);
    double* ys2 = (double*)(ws + WS_YS2_OFF);
    double2* part = (double2*)(ws + WS_PART_OFF);
    float* denom = (float*)(ws + WS_DENOM_OFF);

    // stats + windowed means (all consumed into denom before Hc is written)
    k_reduce_tpl<<<1024, 256, 0, stream>>>((const float4*)tpl, part);
    k_winz<<<NLINES / 256, 256, 0, stream>>>(fr, zs1, zs2);
    k_winy<<<10, 256, 0, stream>>>(zs1, zs2, ys1, ys2);
    k_winx_denom<<<1, 256, 0, stream>>>(ys1, ys2, part, denom);

    // forward: pack (raw) + z-FFT, then y-FFT
    k_pack_fft_z<<<NLINES / 256, 256, 0, stream>>>(fr, tpl, Hc);
    k_fft8<0><<<2048, 512, 0, stream>>>(Hc);

    // fused fwd-x-FFT + cross-power (+DC zero) + inv-x-FFT
    k_fftx_cross<<<4096, 512, 0, stream>>>(Hc);

    // inverse: y-FFT, then z-FFT fused with abs+roll+output
    k_fft8<1><<<2048, 512, 0, stream>>>(Hc);
    k_invz_abs_roll<<<NLINES / 256, 256, 0, stream>>>(Hc, out);

    // ncc + argmax/subpixel (fused)
    k_ncc_argmax<<<1, 256, 0, stream>>>(denom, out);
}

// Round 5
// 403.457 us; speedup vs baseline: 1.6249x; 1.1709x over previous
//
#include <hip/hip_runtime.h>
#include <hip/hip_bf16.h>
#include <math.h>

// ---------------------------------------------------------------------------
// MotionCorrect: FFT-based NCC on 512x512x32 volume (fp32 FFT path, fp64 stats).
//   out = [sh_x, sh_y, sh_z, rolled_cc(512*512*32), ncc(21*21*5)]
// ---------------------------------------------------------------------------

#define NTOT 8388608            // 512*512*32
#define NLINES 262144           // 512*512
#define OUT_ROLL_OFF 3
#define OUT_NCC_OFF 8388611     // 3 + NTOT
#define WIN_PROD 6777792.0      // 492*492*28
#define EPSV 1e-8

// ws layout (bytes)
#define WS_HC_OFF 0UL                       // float2[NTOT] = 67108864 B
#define WS_ZS1_OFF 0UL                      // overlaps Hc (consumed before Hc written)
#define WS_ZS2_OFF 10485760UL
#define WS_YS1_OFF 20971520UL
#define WS_YS2_OFF 21401600UL
#define WS_PART_OFF 31457280UL              // double2[1024] partials (consumed pre-pack)
#define WS_DENOM_OFF 134217728UL            // float[2205] (proven ws range)

typedef float2 cf;
__device__ __forceinline__ cf cfadd(cf a, cf b){ return make_float2(a.x+b.x, a.y+b.y); }
__device__ __forceinline__ cf cfsub(cf a, cf b){ return make_float2(a.x-b.x, a.y-b.y); }
__device__ __forceinline__ cf cfmul(cf a, cf b){ return make_float2(a.x*b.x-a.y*b.y, a.x*b.y+a.y*b.x); }
__device__ __forceinline__ cf cfnegi(cf a){ return make_float2(a.y, -a.x); }   // a * (-i)
__device__ __forceinline__ cf cfposi(cf a){ return make_float2(-a.y, a.x); }   // a * (+i)

#define RT2F 0.70710678118654752440f
// forward eighth-turns: e^{-i pi/4}, e^{-i 3pi/4}
__device__ __forceinline__ cf cw64f(cf v){ return make_float2(RT2F*(v.x+v.y), RT2F*(v.y-v.x)); }
__device__ __forceinline__ cf cw192f(cf v){ return make_float2(RT2F*(v.y-v.x), -RT2F*(v.x+v.y)); }
// inverse eighth-turns: e^{+i pi/4}, e^{+i 3pi/4}
__device__ __forceinline__ cf cw64i(cf v){ return make_float2(RT2F*(v.x-v.y), RT2F*(v.x+v.y)); }
__device__ __forceinline__ cf cw192i(cf v){ return make_float2(-RT2F*(v.x+v.y), RT2F*(v.x-v.y)); }

// Skewed LDS layout (float2 units, b64 ops): one pad slot between 8-blocks.
// addr(i) = i + (i>>3); block k starts at 9k (bank-pairs 9k mod 16 bijective);
// all strided radix-4 passes at exactly 4 lanes/bank-pair (wave64 b64 floor).
#define SKW(i) ((i) + ((i) >> 3))
#define LROW 580                 // >= SKW(511)=574

// ---------------------------------------------------------------------------
// Radix-4 LDS pass, forward (DIF stages 2H,H). tw[t] = (cos, -sin)(2*pi*t/512).
template <int H>
__device__ __forceinline__ void fwd_r4(cf* ln, const cf* tw, int lane) {
    const int MUL2 = 256 / (2 * H);
#pragma unroll
    for (int g = 0; g < 2; ++g) {
        int j = lane + 64 * g;                    // 0..127
        int t = j & (H - 1);
        int i0 = ((j & ~(H - 1)) << 2) + t;
        cf A = ln[SKW(i0)];
        cf B = ln[SKW(i0 + H)];
        cf C = ln[SKW(i0 + 2 * H)];
        cf D = ln[SKW(i0 + 3 * H)];
        cf w1 = tw[t * MUL2];
        cf w2 = make_float2(w1.x * w1.x - w1.y * w1.y, 2.0f * w1.x * w1.y);   // w1^2
        cf u = cfadd(A, C), v = cfadd(B, D);
        cf p = cfmul(cfsub(A, C), w1);
        cf q = cfnegi(cfmul(cfsub(B, D), w1));    // W^{(t+H)m} = -i*w1
        ln[SKW(i0)]         = cfadd(u, v);
        ln[SKW(i0 + H)]     = cfmul(cfsub(u, v), w2);
        ln[SKW(i0 + 2 * H)] = cfadd(p, q);
        ln[SKW(i0 + 3 * H)] = cfmul(cfsub(p, q), w2);
    }
}

// inverse (DIT stages H,2H), conjugate twiddles
template <int H>
__device__ __forceinline__ void inv_r4(cf* ln, const cf* tw, int lane) {
    const int MUL2 = 256 / (2 * H);
#pragma unroll
    for (int g = 0; g < 2; ++g) {
        int j = lane + 64 * g;
        int t = j & (H - 1);
        int i0 = ((j & ~(H - 1)) << 2) + t;
        cf A = ln[SKW(i0)];
        cf B = ln[SKW(i0 + H)];
        cf C = ln[SKW(i0 + 2 * H)];
        cf D = ln[SKW(i0 + 3 * H)];
        cf tww = tw[t * MUL2];
        cf w2 = make_float2(tww.x, -tww.y);       // conj
        cf wH = make_float2(w2.x * w2.x - w2.y * w2.y, 2.0f * w2.x * w2.y);
        cf vb = cfmul(B, wH), vd = cfmul(D, wH);
        cf a0 = cfadd(A, vb), a1 = cfsub(A, vb);
        cf c0 = cfadd(C, vd), c1 = cfsub(C, vd);
        cf t0 = cfmul(c0, w2);
        cf t1 = cfposi(cfmul(c1, w2));            // W^{+(t+H)m} = +i*w2
        ln[SKW(i0)]         = cfadd(a0, t0);
        ln[SKW(i0 + 2 * H)] = cfsub(a0, t0);
        ln[SKW(i0 + H)]     = cfadd(a1, t1);
        ln[SKW(i0 + 3 * H)] = cfsub(a1, t1);
    }
}

// Register radix-8 tail: forward DIF stages h=4,2,1 on contiguous 8-blocks
// (block k contiguous at [9k, 9k+8) float2 slots).
__device__ __forceinline__ void fwd_r8(cf* ln, int lane) {
    cf* rp = ln + 9 * lane;
    cf L0 = rp[0], L1 = rp[1], L2 = rp[2], L3 = rp[3];
    cf L4 = rp[4], L5 = rp[5], L6 = rp[6], L7 = rp[7];
    cf s0 = cfadd(L0, L4), d0 = cfsub(L0, L4);
    cf s1 = cfadd(L1, L5), d1 = cw64f(cfsub(L1, L5));
    cf s2 = cfadd(L2, L6), d2 = cfnegi(cfsub(L2, L6));
    cf s3 = cfadd(L3, L7), d3 = cw192f(cfsub(L3, L7));
    cf e0 = cfadd(s0, s2), e2 = cfsub(s0, s2);
    cf e1 = cfadd(s1, s3), e3 = cfnegi(cfsub(s1, s3));
    cf f0 = cfadd(d0, d2), f2 = cfsub(d0, d2);
    cf f1 = cfadd(d1, d3), f3 = cfnegi(cfsub(d1, d3));
    rp[0] = cfadd(e0, e1); rp[1] = cfsub(e0, e1);
    rp[2] = cfadd(e2, e3); rp[3] = cfsub(e2, e3);
    rp[4] = cfadd(f0, f1); rp[5] = cfsub(f0, f1);
    rp[6] = cfadd(f2, f3); rp[7] = cfsub(f2, f3);
}

// inverse DIT stages h=1,2,4
__device__ __forceinline__ void inv_r8(cf* ln, int lane) {
    cf* rp = ln + 9 * lane;
    cf L0 = rp[0], L1 = rp[1], L2 = rp[2], L3 = rp[3];
    cf L4 = rp[4], L5 = rp[5], L6 = rp[6], L7 = rp[7];
    cf a0 = cfadd(L0, L1), a1 = cfsub(L0, L1), a2 = cfadd(L2, L3), a3 = cfsub(L2, L3);
    cf a4 = cfadd(L4, L5), a5 = cfsub(L4, L5), a6 = cfadd(L6, L7), a7 = cfsub(L6, L7);
    cf b0 = cfadd(a0, a2), b2 = cfsub(a0, a2);
    cf v13 = cfposi(a3);
    cf b1 = cfadd(a1, v13), b3 = cfsub(a1, v13);
    cf b4 = cfadd(a4, a6), b6 = cfsub(a4, a6);
    cf v57 = cfposi(a7);
    cf b5 = cfadd(a5, v57), b7 = cfsub(a5, v57);
    cf v0 = b4, v1 = cw64i(b5), v2 = cfposi(b6), v3 = cw192i(b7);
    rp[0] = cfadd(b0, v0); rp[4] = cfsub(b0, v0);
    rp[1] = cfadd(b1, v1); rp[5] = cfsub(b1, v1);
    rp[2] = cfadd(b2, v2); rp[6] = cfsub(b2, v2);
    rp[3] = cfadd(b3, v3); rp[7] = cfsub(b3, v3);
}

// full 512-point line FFT: one wave per line, wave_barrier pins ordering
template <int INV>
__device__ __forceinline__ void line_fft512(cf* ln, const cf* tw, int lane) {
    if (!INV) {
        fwd_r4<128>(ln, tw, lane);
        __builtin_amdgcn_wave_barrier();
        fwd_r4<32>(ln, tw, lane);
        __builtin_amdgcn_wave_barrier();
        fwd_r4<8>(ln, tw, lane);
        __builtin_amdgcn_wave_barrier();
        fwd_r8(ln, lane);
    } else {
        inv_r8(ln, lane);
        __builtin_amdgcn_wave_barrier();
        inv_r4<8>(ln, tw, lane);
        __builtin_amdgcn_wave_barrier();
        inv_r4<32>(ln, tw, lane);
        __builtin_amdgcn_wave_barrier();
        inv_r4<128>(ln, tw, lane);
    }
}

// ---------------------------------------------------------------------------
// per-thread radix-2 FFT of length 32 (z-axis), fp32
static constexpr float W32CF_[16] = {
    1.0f, 0.980785280403230449f, 0.923879532511286756f, 0.831469612302545237f,
    0.707106781186547524f, 0.555570233019602225f, 0.382683432365089772f, 0.195090322016128268f,
    0.0f, -0.195090322016128268f, -0.382683432365089772f, -0.555570233019602225f,
    -0.707106781186547524f, -0.831469612302545237f, -0.923879532511286756f, -0.980785280403230449f};
static constexpr float W32SF_[16] = {
    0.0f, 0.195090322016128268f, 0.382683432365089772f, 0.555570233019602225f,
    0.707106781186547524f, 0.831469612302545237f, 0.923879532511286756f, 0.980785280403230449f,
    1.0f, 0.980785280403230449f, 0.923879532511286756f, 0.831469612302545237f,
    0.707106781186547524f, 0.555570233019602225f, 0.382683432365089772f, 0.195090322016128268f};

template <int INV>
__device__ __forceinline__ void fft32(cf* a) {
    if (INV == 0) {
#pragma unroll
        for (int s = 0; s < 5; ++s) {
            const int h = 16 >> s;
#pragma unroll
            for (int j = 0; j < 16; ++j) {
                const int t = j & (h - 1);
                const int i0 = ((j >> (4 - s)) << (5 - s)) + t;
                const int i1 = i0 + h;
                cf u = a[i0], v = a[i1];
                a[i0] = make_float2(u.x + v.x, u.y + v.y);
                float dx = u.x - v.x, dy = u.y - v.y;
                const float wc = W32CF_[t << s];
                const float ws = -W32SF_[t << s];
                a[i1] = make_float2(dx * wc - dy * ws, dx * ws + dy * wc);
            }
        }
    } else {
#pragma unroll
        for (int s = 0; s < 5; ++s) {
            const int h = 1 << s;
#pragma unroll
            for (int j = 0; j < 16; ++j) {
                const int t = j & (h - 1);
                const int i0 = ((j >> s) << (s + 1)) + t;
                const int i1 = i0 + h;
                const float wc = W32CF_[t << (4 - s)];
                const float ws = W32SF_[t << (4 - s)];
                cf u = a[i0], vr = a[i1];
                cf v = make_float2(vr.x * wc - vr.y * ws, vr.x * ws + vr.y * wc);
                a[i0] = make_float2(u.x + v.x, u.y + v.y);
                a[i1] = make_float2(u.x - v.x, u.y - v.y);
            }
        }
    }
}

// bit-reversed-storage mirror of frequency negation (involution), any 2^k size
__device__ __forceinline__ int mir_br(int b) {
    if (b == 0) return 0;
    int s = 31 - __clz(b);
    return (3 << s) - 1 - b;
}

// ---------------------------------------------------------------------------
// K1: template sums -> per-block partials (fp64, no atomics)
__global__ __launch_bounds__(256) void k_reduce_tpl(const float4* __restrict__ tpl4,
                                                    double2* __restrict__ part) {
    double st = 0, st2 = 0;
    const int stride = gridDim.x * blockDim.x;
    for (int i = blockIdx.x * blockDim.x + threadIdx.x; i < NTOT / 4; i += stride) {
        float4 t = tpl4[i];
        double t0 = t.x, t1 = t.y, t2 = t.z, t3 = t.w;
        st += t0 + t1 + t2 + t3;
        st2 += t0 * t0 + t1 * t1 + t2 * t2 + t3 * t3;
    }
    __shared__ double s1[256], s2[256];
    int tid = threadIdx.x;
    s1[tid] = st; s2[tid] = st2;
    __syncthreads();
    for (int s = 128; s > 0; s >>= 1) {
        if (tid < s) { s1[tid] += s1[tid + s]; s2[tid] += s2[tid + s]; }
        __syncthreads();
    }
    if (tid == 0) part[blockIdx.x] = make_double2(s1[0], s2[0]);
}

// ---------------------------------------------------------------------------
// K2: z-direction sliding-window sums (28 of 32 -> 5), fp64
__global__ __launch_bounds__(256) void k_winz(const float* __restrict__ img,
                                              double* __restrict__ zs1,
                                              double* __restrict__ zs2) {
    int line = blockIdx.x * blockDim.x + threadIdx.x;
    long b = (long)line << 5;
    float v[32];
    const float4* p4 = (const float4*)(img + b);
#pragma unroll
    for (int q = 0; q < 8; ++q) {
        float4 f = p4[q];
        v[q * 4 + 0] = f.x; v[q * 4 + 1] = f.y; v[q * 4 + 2] = f.z; v[q * 4 + 3] = f.w;
    }
    double s1 = 0, s2 = 0;
#pragma unroll
    for (int z = 0; z < 28; ++z) {
        double t = (double)v[z];
        s1 += t;
        s2 += t * t;
    }
    long ob = (long)line * 5;
    zs1[ob] = s1; zs2[ob] = s2;
#pragma unroll
    for (int k = 1; k <= 4; ++k) {
        double a = (double)v[27 + k], r = (double)v[k - 1];
        s1 += a - r;
        s2 += a * a - r * r;
        zs1[ob + k] = s1; zs2[ob + k] = s2;
    }
}

// K3: y-direction sliding window (492 of 512 -> 21)
__global__ __launch_bounds__(256) void k_winy(const double* __restrict__ zs1,
                                              const double* __restrict__ zs2,
                                              double* __restrict__ ys1,
                                              double* __restrict__ ys2) {
    int t = blockIdx.x * blockDim.x + threadIdx.x;
    if (t >= 2560) return;
    int x = t / 5, c = t % 5;
    long base = (long)x * 512 * 5 + c;
    double s1 = 0, s2 = 0;
    for (int y = 0; y < 492; ++y) {
        s1 += zs1[base + (long)y * 5];
        s2 += zs2[base + (long)y * 5];
    }
    long ob = (long)x * 105 + c;
    ys1[ob] = s1; ys2[ob] = s2;
    for (int k = 1; k <= 20; ++k) {
        s1 += zs1[base + (long)(491 + k) * 5] - zs1[base + (long)(k - 1) * 5];
        s2 += zs2[base + (long)(491 + k) * 5] - zs2[base + (long)(k - 1) * 5];
        ys1[ob + (long)k * 5] = s1;
        ys2[ob + (long)k * 5] = s2;
    }
}

// K4: reduce tpl partials -> tpl_var, then x-direction sliding window + denom
__global__ __launch_bounds__(256) void k_winx_denom(const double* __restrict__ ys1,
                                                    const double* __restrict__ ys2,
                                                    const double2* __restrict__ part,
                                                    float* __restrict__ denom) {
    __shared__ double s1s[256], s2s[256];
    __shared__ double tplvar_s;
    int tid = threadIdx.x;
    {
        double a1 = 0, a2 = 0;
#pragma unroll
        for (int q = 0; q < 4; ++q) {
            double2 p = part[tid + 256 * q];
            a1 += p.x; a2 += p.y;
        }
        s1s[tid] = a1; s2s[tid] = a2;
        __syncthreads();
        for (int s = 128; s > 0; s >>= 1) {
            if (tid < s) { s1s[tid] += s1s[tid + s]; s2s[tid] += s2s[tid + s]; }
            __syncthreads();
        }
        if (tid == 0) {
            double S1 = s1s[0], S2 = s2s[0];
            double mu = S1 / (double)NTOT;
            tplvar_s = S2 - (double)NTOT * mu * mu + EPSV;
        }
        __syncthreads();
    }
    if (tid >= 105) return;
    const double tpl_var = tplvar_s;
    double s1 = 0, s2 = 0;
    for (int x = 0; x < 492; ++x) {
        s1 += ys1[(long)x * 105 + tid];
        s2 += ys2[(long)x * 105 + tid];
    }
    const double wm = 1.0 / WIN_PROD;
    for (int a = 0; a < 21; ++a) {
        double m1 = s1 * wm, m2 = s2 * wm;
        double iv = m2 - (m1 * m1) / (double)NTOT + EPSV;
        if (iv < 0) iv = 0;
        denom[a * 105 + tid] = (float)sqrt(tpl_var * iv);
        if (a < 20) {
            s1 += ys1[(long)(492 + a) * 105 + tid] - ys1[(long)a * 105 + tid];
            s2 += ys2[(long)(492 + a) * 105 + tid] - ys2[(long)a * 105 + tid];
        }
    }
}

// ---------------------------------------------------------------------------
// K5: pack h = img + i*tpl (raw; mean handled via DC-bin zeroing), fwd z-FFT
__global__ __launch_bounds__(256) void k_pack_fft_z(const float* __restrict__ img,
                                                    const float* __restrict__ tpl,
                                                    cf* __restrict__ d) {
    int line = blockIdx.x * blockDim.x + threadIdx.x;
    long b = (long)line << 5;
    cf a[32];
    const float4* pi4 = (const float4*)(img + b);
    const float4* pt4 = (const float4*)(tpl + b);
#pragma unroll
    for (int q = 0; q < 8; ++q) {
        float4 fi = pi4[q];
        float4 ft = pt4[q];
        a[q * 4 + 0] = make_float2(fi.x, ft.x);
        a[q * 4 + 1] = make_float2(fi.y, ft.y);
        a[q * 4 + 2] = make_float2(fi.z, ft.z);
        a[q * 4 + 3] = make_float2(fi.w, ft.w);
    }
    fft32<0>(a);
#pragma unroll
    for (int z = 0; z < 32; ++z) d[b + z] = a[z];
}

// ---------------------------------------------------------------------------
// K6/K8: y-direction 512-point line FFT. 16 lines (16 consecutive z) per
// 1024-thread block (one wave per line) -> 128 B global segments.
template <int INV>
__global__ __launch_bounds__(1024, 8) void k_fft16(cf* __restrict__ d) {
    __shared__ cf ln[16][LROW];
    __shared__ cf tw[256];
    const int tid = threadIdx.x;
    if (tid < 256) {
        double sv, cv;
        sincos(6.283185307179586476925286766559 * (double)tid / 512.0, &sv, &cv);
        tw[tid] = make_float2((float)cv, (float)(-sv));   // fwd sign; inv conjugates
    }
    const long base = (long)(blockIdx.x >> 1) * 16384 + (blockIdx.x & 1) * 16;
#pragma unroll
    for (int i = 0; i < 8; ++i) {
        int idx = tid + 1024 * i;
        int lz = idx & 15, e = idx >> 4;          // 16 lanes = 128 B contiguous
        ln[lz][SKW(e)] = d[base + (long)e * 32 + lz];
    }
    __syncthreads();
    const int c = tid >> 6, lane = tid & 63;
    line_fft512<INV>(ln[c], tw, lane);
    __syncthreads();
#pragma unroll
    for (int i = 0; i < 8; ++i) {
        int idx = tid + 1024 * i;
        int lz = idx & 15, e = idx >> 4;
        d[base + (long)e * 32 + lz] = ln[lz][SKW(e)];
    }
}

// ---------------------------------------------------------------------------
// K7: fused forward-x-FFT + cross-power + inverse-x-FFT.
// Block: A = (y, 8-z tile tA) + B = (mir_br(y), tB) with tB = tA ^ (tA>>1)
// (8-z dyadic mirror: {0->0, 1->1, 2<->3}). 16 lines, 1024 threads.
__global__ __launch_bounds__(1024, 8) void k_fftx_cross(cf* __restrict__ d) {
    const int bid = blockIdx.x;
    const int y = bid >> 2, tA = bid & 3;
    const int my = mir_br(y);
    const int tB = tA ^ (tA >> 1);
    const int keyA = (y << 2) | tA, keyB = (my << 2) | tB;
    if (keyA > keyB) return;                      // canonical pair only
    const bool dup = (keyA == keyB);

    __shared__ cf ln[16][LROW];
    __shared__ cf tw[256];
    const int tid = threadIdx.x;
    if (tid < 256) {
        double sv, cv;
        sincos(6.283185307179586476925286766559 * (double)tid / 512.0, &sv, &cv);
        tw[tid] = make_float2((float)cv, (float)(-sv));
    }
    const int baseA = y * 32 + tA * 8;
    const int baseB = my * 32 + tB * 8;
#pragma unroll
    for (int i = 0; i < 8; ++i) {
        int idx = tid + 1024 * i;
        int a = idx & 7, half = (idx >> 3) & 1, bx = idx >> 4;
        ln[half * 8 + a][SKW(bx)] = d[(long)bx * 16384 + (half ? baseB : baseA) + a];
    }
    __syncthreads();
    const int c = tid >> 6, lane = tid & 63;
    line_fft512<0>(ln[c], tw, lane);
    __syncthreads();
    // cross-power: H = F + iG packed; P = F*conj(G); P(-k) = conj(P(k)).
    // A-rows [0..7] are sources, partners written into B-rows [8..15]
    // ((a,bx)->(am,mbx) is a bijection -> race-free without barrier).
    // Within-tile z-line mirror: tile0 -> mir_br(a); tiles 1,2,3 -> 7-a.
    const bool dcblk = (bid == 0);
#pragma unroll
    for (int i = 0; i < 4; ++i) {
        int p = tid + 1024 * i;                   // 0..4095
        int a = p >> 9, bx = p & 511;
        int am = (tA == 0) ? mir_br(a) : 7 - a;
        int mbx = mir_br(bx);
        if (dcblk && p == 0) {                    // zero-mean => DC bin = 0
            ln[0][0] = make_float2(0.f, 0.f);
            ln[8][0] = make_float2(0.f, 0.f);
            continue;
        }
        cf h1 = ln[a][SKW(bx)];
        cf h2 = ln[8 + am][SKW(mbx)];
        float Fr = 0.5f * (h1.x + h2.x), Fi = 0.5f * (h1.y - h2.y);
        float Gr = 0.5f * (h1.y + h2.y), Gi = 0.5f * (h2.x - h1.x);
        float Pr = Fr * Gr + Fi * Gi;
        float Pi = Fi * Gr - Fr * Gi;
        ln[a][SKW(bx)] = make_float2(Pr, Pi);
        ln[8 + am][SKW(mbx)] = make_float2(Pr, -Pi);
    }
    __syncthreads();
    line_fft512<1>(ln[c], tw, lane);
    __syncthreads();
#pragma unroll
    for (int i = 0; i < 8; ++i) {
        int idx = tid + 1024 * i;
        int a = idx & 7, half = (idx >> 3) & 1, bx = idx >> 4;
        if (dup && half) continue;                // self-paired: skip dup stores
        d[(long)bx * 16384 + (half ? baseB : baseA) + a] = ln[half * 8 + a][SKW(bx)];
    }
}

// ---------------------------------------------------------------------------
// K9: inverse DIT FFT along z, |.|/N, roll by (256,256,16), write rolled_cc
__global__ __launch_bounds__(256) void k_invz_abs_roll(const cf* __restrict__ d,
                                                       float* __restrict__ out) {
    int line = blockIdx.x * blockDim.x + threadIdx.x;
    int x = line >> 9, y = line & 511;
    long b = (long)line << 5;
    cf a[32];
#pragma unroll
    for (int z = 0; z < 32; ++z) a[z] = d[b + z];
    fft32<1>(a);
    const float invN = 1.0f / 8388608.0f;
    int xo = (x + 256) & 511, yo = (y + 256) & 511;
    long ob = OUT_ROLL_OFF + ((long)(xo << 9 | yo) << 5);
#pragma unroll
    for (int q = 0; q < 8; ++q) {
        int z = q * 4;
        int zo = (z + 16) & 31;
        float4 w;
        w.x = sqrtf(a[z + 0].x * a[z + 0].x + a[z + 0].y * a[z + 0].y) * invN;
        w.y = sqrtf(a[z + 1].x * a[z + 1].x + a[z + 1].y * a[z + 1].y) * invN;
        w.z = sqrtf(a[z + 2].x * a[z + 2].x + a[z + 2].y * a[z + 2].y) * invN;
        w.w = sqrtf(a[z + 3].x * a[z + 3].x + a[z + 3].y * a[z + 3].y) * invN;
        *(float4*)(out + ob + zo) = w;
    }
}

// ---------------------------------------------------------------------------
// K10: fused ncc + argmax (first-max) + log-Gaussian subpixel refine
__global__ __launch_bounds__(256) void k_ncc_argmax(const float* __restrict__ denom,
                                                    float* __restrict__ out) {
    __shared__ float sncc[2205];
    __shared__ float bv[256];
    __shared__ int bi[256];
    const int tid = threadIdx.x;
    float best = -INFINITY;
    int bidx = 0x7fffffff;
    for (int i = tid; i < 2205; i += 256) {
        int a = i / 105, r = i % 105;
        int bq = r / 5, cq = r % 5;
        long ridx = OUT_ROLL_OFF + ((long)((246 + a) * 512 + (246 + bq)) << 5) + (14 + cq);
        float v = out[ridx] / denom[i];
        if (isnan(v)) v = 0.f;
        out[OUT_NCC_OFF + i] = v;
        sncc[i] = v;
        if (v > best) { best = v; bidx = i; }
    }
    bv[tid] = best;
    bi[tid] = bidx;
    __syncthreads();
    for (int s = 128; s > 0; s >>= 1) {
        if (tid < s) {
            if (bv[tid + s] > bv[tid] || (bv[tid + s] == bv[tid] && bi[tid + s] < bi[tid])) {
                bv[tid] = bv[tid + s];
                bi[tid] = bi[tid + s];
            }
        }
        __syncthreads();
    }
    if (tid == 0) {
        int idx = bi[0];
        int sx = idx / 105, sy = (idx % 105) / 5, sz = idx % 5;
        auto cl = [](int v, int n) { return v < 0 ? 0 : (v >= n ? n - 1 : v); };
        auto V = [&](int dx, int dy, int dz) {
            return logf(sncc[cl(sx + dx, 21) * 105 + cl(sy + dy, 21) * 5 + cl(sz + dz, 5)]);
        };
        float v0 = V(0, 0, 0);
        float six = 6.0f * v0;
        float am = V(-1, 0, 0), ap = V(1, 0, 0);
        float bm = V(0, -1, 0), bp = V(0, 1, 0);
        float cm = V(0, 0, -1), cp = V(0, 0, 1);
        out[0] = (float)(-(sx - 10)) - (am - ap) / (2.f * am - six + 2.f * ap);
        out[1] = (float)(-(sy - 10)) - (bm - bp) / (2.f * bm - six + 2.f * bp);
        out[2] = (float)(-(sz - 2)) - (cm - cp) / (2.f * cm - six + 2.f * cp);
    }
}

// ---------------------------------------------------------------------------
extern "C" void kernel_launch(void* const* d_in, const int* in_sizes, int n_in,
                              void* d_out, int out_size, void* d_ws, size_t ws_size,
                              hipStream_t stream) {
    const float* fr = (const float*)d_in[0];
    const float* tpl = (const float*)d_in[1];
    float* out = (float*)d_out;
    char* ws = (char*)d_ws;

    cf* Hc = (cf*)(ws + WS_HC_OFF);
    double* zs1 = (double*)(ws + WS_ZS1_OFF);
    double* zs2 = (double*)(ws + WS_ZS2_OFF);
    double* ys1 = (double*)(ws + WS_YS1_OFF);
    double* ys2 = (double*)(ws + WS_YS2_OFF);
    double2* part = (double2*)(ws + WS_PART_OFF);
    float* denom = (float*)(ws + WS_DENOM_OFF);

    // stats + windowed means (all consumed into denom before Hc is written)
    k_reduce_tpl<<<1024, 256, 0, stream>>>((const float4*)tpl, part);
    k_winz<<<NLINES / 256, 256, 0, stream>>>(fr, zs1, zs2);
    k_winy<<<10, 256, 0, stream>>>(zs1, zs2, ys1, ys2);
    k_winx_denom<<<1, 256, 0, stream>>>(ys1, ys2, part, denom);

    // forward: pack (raw) + z-FFT, then y-FFT
    k_pack_fft_z<<<NLINES / 256, 256, 0, stream>>>(fr, tpl, Hc);
    k_fft16<0><<<1024, 1024, 0, stream>>>(Hc);

    // fused fwd-x-FFT + cross-power (+DC zero) + inv-x-FFT
    k_fftx_cross<<<2048, 1024, 0, stream>>>(Hc);

    // inverse: y-FFT, then z-FFT fused with abs+roll+output
    k_fft16<1><<<1024, 1024, 0, stream>>>(Hc);
    k_invz_abs_roll<<<NLINES / 256, 256, 0, stream>>>(Hc, out);

    // ncc + argmax/subpixel (fused)
    k_ncc_argmax<<<1, 256, 0, stream>>>(denom, out);
}

// Round 7
// 392.879 us; speedup vs baseline: 1.6686x; 1.0269x over previous
//
#include <hip/hip_runtime.h>
#include <hip/hip_bf16.h>
#include <math.h>

// ---------------------------------------------------------------------------
// MotionCorrect: FFT-based NCC on 512x512x32 volume (fp32 FFT path, fp64 stats).
//   out = [sh_x, sh_y, sh_z, rolled_cc(512*512*32), ncc(21*21*5)]
// ---------------------------------------------------------------------------

#define NTOT 8388608            // 512*512*32
#define NLINES 262144           // 512*512
#define OUT_ROLL_OFF 3
#define OUT_NCC_OFF 8388611     // 3 + NTOT
#define WIN_PROD 6777792.0      // 492*492*28
#define EPSV 1e-8

// ws layout (bytes) -- zs/ys/part PAST Hc (no overlap, no ordering hazard)
#define WS_HC_OFF 0UL                       // float2[NTOT] = 67108864 B
#define WS_ZS1_OFF 67108864UL               // double[NLINES*5] = 10485760 B
#define WS_ZS2_OFF 77594624UL
#define WS_YS1_OFF 88080384UL               // double[512*105] = 430080 B
#define WS_YS2_OFF 88510464UL
#define WS_PART_OFF 88940544UL              // double2[1024]
#define WS_DENOM_OFF 88957952UL             // float[2205]

typedef float2 cf;
__device__ __forceinline__ cf cfadd(cf a, cf b){ return make_float2(a.x+b.x, a.y+b.y); }
__device__ __forceinline__ cf cfsub(cf a, cf b){ return make_float2(a.x-b.x, a.y-b.y); }
__device__ __forceinline__ cf cfmul(cf a, cf b){ return make_float2(a.x*b.x-a.y*b.y, a.x*b.y+a.y*b.x); }
__device__ __forceinline__ cf cfnegi(cf a){ return make_float2(a.y, -a.x); }   // a * (-i)
__device__ __forceinline__ cf cfposi(cf a){ return make_float2(-a.y, a.x); }   // a * (+i)

#define RT2F 0.70710678118654752440f
// forward eighth-turns: e^{-i pi/4}, e^{-i 3pi/4}
__device__ __forceinline__ cf cw64f(cf v){ return make_float2(RT2F*(v.x+v.y), RT2F*(v.y-v.x)); }
__device__ __forceinline__ cf cw192f(cf v){ return make_float2(RT2F*(v.y-v.x), -RT2F*(v.x+v.y)); }
// inverse eighth-turns: e^{+i pi/4}, e^{+i 3pi/4}
__device__ __forceinline__ cf cw64i(cf v){ return make_float2(RT2F*(v.x-v.y), RT2F*(v.x+v.y)); }
__device__ __forceinline__ cf cw192i(cf v){ return make_float2(-RT2F*(v.x+v.y), RT2F*(v.x-v.y)); }

// Skewed LDS layout (float2 units): one pad slot between 8-blocks.
#define SKW(i) ((i) + ((i) >> 3))
#define LROW 580                 // >= SKW(511)=574

// ---------------------------------------------------------------------------
// Radix-4 LDS pass, forward (DIF stages 2H,H). tw[t] = (cos, -sin)(2*pi*t/512).
template <int H>
__device__ __forceinline__ void fwd_r4(cf* ln, const cf* tw, int lane) {
    const int MUL2 = 256 / (2 * H);
#pragma unroll
    for (int g = 0; g < 2; ++g) {
        int j = lane + 64 * g;                    // 0..127
        int t = j & (H - 1);
        int i0 = ((j & ~(H - 1)) << 2) + t;
        cf A = ln[SKW(i0)];
        cf B = ln[SKW(i0 + H)];
        cf C = ln[SKW(i0 + 2 * H)];
        cf D = ln[SKW(i0 + 3 * H)];
        cf w1 = tw[t * MUL2];
        cf w2 = make_float2(w1.x * w1.x - w1.y * w1.y, 2.0f * w1.x * w1.y);   // w1^2
        cf u = cfadd(A, C), v = cfadd(B, D);
        cf p = cfmul(cfsub(A, C), w1);
        cf q = cfnegi(cfmul(cfsub(B, D), w1));    // W^{(t+H)m} = -i*w1
        ln[SKW(i0)]         = cfadd(u, v);
        ln[SKW(i0 + H)]     = cfmul(cfsub(u, v), w2);
        ln[SKW(i0 + 2 * H)] = cfadd(p, q);
        ln[SKW(i0 + 3 * H)] = cfmul(cfsub(p, q), w2);
    }
}

// inverse (DIT stages H,2H), conjugate twiddles
template <int H>
__device__ __forceinline__ void inv_r4(cf* ln, const cf* tw, int lane) {
    const int MUL2 = 256 / (2 * H);
#pragma unroll
    for (int g = 0; g < 2; ++g) {
        int j = lane + 64 * g;
        int t = j & (H - 1);
        int i0 = ((j & ~(H - 1)) << 2) + t;
        cf A = ln[SKW(i0)];
        cf B = ln[SKW(i0 + H)];
        cf C = ln[SKW(i0 + 2 * H)];
        cf D = ln[SKW(i0 + 3 * H)];
        cf tww = tw[t * MUL2];
        cf w2 = make_float2(tww.x, -tww.y);       // conj
        cf wH = make_float2(w2.x * w2.x - w2.y * w2.y, 2.0f * w2.x * w2.y);
        cf vb = cfmul(B, wH), vd = cfmul(D, wH);
        cf a0 = cfadd(A, vb), a1 = cfsub(A, vb);
        cf c0 = cfadd(C, vd), c1 = cfsub(C, vd);
        cf t0 = cfmul(c0, w2);
        cf t1 = cfposi(cfmul(c1, w2));            // W^{+(t+H)m} = +i*w2
        ln[SKW(i0)]         = cfadd(a0, t0);
        ln[SKW(i0 + 2 * H)] = cfsub(a0, t0);
        ln[SKW(i0 + H)]     = cfadd(a1, t1);
        ln[SKW(i0 + 3 * H)] = cfsub(a1, t1);
    }
}

// Register radix-8 tail: forward DIF stages h=4,2,1 on contiguous 8-blocks
__device__ __forceinline__ void fwd_r8(cf* ln, int lane) {
    cf* rp = ln + 9 * lane;
    cf L0 = rp[0], L1 = rp[1], L2 = rp[2], L3 = rp[3];
    cf L4 = rp[4], L5 = rp[5], L6 = rp[6], L7 = rp[7];
    cf s0 = cfadd(L0, L4), d0 = cfsub(L0, L4);
    cf s1 = cfadd(L1, L5), d1 = cw64f(cfsub(L1, L5));
    cf s2 = cfadd(L2, L6), d2 = cfnegi(cfsub(L2, L6));
    cf s3 = cfadd(L3, L7), d3 = cw192f(cfsub(L3, L7));
    cf e0 = cfadd(s0, s2), e2 = cfsub(s0, s2);
    cf e1 = cfadd(s1, s3), e3 = cfnegi(cfsub(s1, s3));
    cf f0 = cfadd(d0, d2), f2 = cfsub(d0, d2);
    cf f1 = cfadd(d1, d3), f3 = cfnegi(cfsub(d1, d3));
    rp[0] = cfadd(e0, e1); rp[1] = cfsub(e0, e1);
    rp[2] = cfadd(e2, e3); rp[3] = cfsub(e2, e3);
    rp[4] = cfadd(f0, f1); rp[5] = cfsub(f0, f1);
    rp[6] = cfadd(f2, f3); rp[7] = cfsub(f2, f3);
}

// inverse DIT stages h=1,2,4
__device__ __forceinline__ void inv_r8(cf* ln, int lane) {
    cf* rp = ln + 9 * lane;
    cf L0 = rp[0], L1 = rp[1], L2 = rp[2], L3 = rp[3];
    cf L4 = rp[4], L5 = rp[5], L6 = rp[6], L7 = rp[7];
    cf a0 = cfadd(L0, L1), a1 = cfsub(L0, L1), a2 = cfadd(L2, L3), a3 = cfsub(L2, L3);
    cf a4 = cfadd(L4, L5), a5 = cfsub(L4, L5), a6 = cfadd(L6, L7), a7 = cfsub(L6, L7);
    cf b0 = cfadd(a0, a2), b2 = cfsub(a0, a2);
    cf v13 = cfposi(a3);
    cf b1 = cfadd(a1, v13), b3 = cfsub(a1, v13);
    cf b4 = cfadd(a4, a6), b6 = cfsub(a4, a6);
    cf v57 = cfposi(a7);
    cf b5 = cfadd(a5, v57), b7 = cfsub(a5, v57);
    cf v0 = b4, v1 = cw64i(b5), v2 = cfposi(b6), v3 = cw192i(b7);
    rp[0] = cfadd(b0, v0); rp[4] = cfsub(b0, v0);
    rp[1] = cfadd(b1, v1); rp[5] = cfsub(b1, v1);
    rp[2] = cfadd(b2, v2); rp[6] = cfsub(b2, v2);
    rp[3] = cfadd(b3, v3); rp[7] = cfsub(b3, v3);
}

// full 512-point line FFT: one wave per line, wave_barrier pins ordering
template <int INV>
__device__ __forceinline__ void line_fft512(cf* ln, const cf* tw, int lane) {
    if (!INV) {
        fwd_r4<128>(ln, tw, lane);
        __builtin_amdgcn_wave_barrier();
        fwd_r4<32>(ln, tw, lane);
        __builtin_amdgcn_wave_barrier();
        fwd_r4<8>(ln, tw, lane);
        __builtin_amdgcn_wave_barrier();
        fwd_r8(ln, lane);
    } else {
        inv_r8(ln, lane);
        __builtin_amdgcn_wave_barrier();
        inv_r4<8>(ln, tw, lane);
        __builtin_amdgcn_wave_barrier();
        inv_r4<32>(ln, tw, lane);
        __builtin_amdgcn_wave_barrier();
        inv_r4<128>(ln, tw, lane);
    }
}

// ---------------------------------------------------------------------------
// per-thread radix-2 FFT of length 32 (z-axis), fp32
static constexpr float W32CF_[16] = {
    1.0f, 0.980785280403230449f, 0.923879532511286756f, 0.831469612302545237f,
    0.707106781186547524f, 0.555570233019602225f, 0.382683432365089772f, 0.195090322016128268f,
    0.0f, -0.195090322016128268f, -0.382683432365089772f, -0.555570233019602225f,
    -0.707106781186547524f, -0.831469612302545237f, -0.923879532511286756f, -0.980785280403230449f};
static constexpr float W32SF_[16] = {
    0.0f, 0.195090322016128268f, 0.382683432365089772f, 0.555570233019602225f,
    0.707106781186547524f, 0.831469612302545237f, 0.923879532511286756f, 0.980785280403230449f,
    1.0f, 0.980785280403230449f, 0.923879532511286756f, 0.831469612302545237f,
    0.707106781186547524f, 0.555570233019602225f, 0.382683432365089772f, 0.195090322016128268f};

template <int INV>
__device__ __forceinline__ void fft32(cf* a) {
    if (INV == 0) {
#pragma unroll
        for (int s = 0; s < 5; ++s) {
            const int h = 16 >> s;
#pragma unroll
            for (int j = 0; j < 16; ++j) {
                const int t = j & (h - 1);
                const int i0 = ((j >> (4 - s)) << (5 - s)) + t;
                const int i1 = i0 + h;
                cf u = a[i0], v = a[i1];
                a[i0] = make_float2(u.x + v.x, u.y + v.y);
                float dx = u.x - v.x, dy = u.y - v.y;
                const float wc = W32CF_[t << s];
                const float ws = -W32SF_[t << s];
                a[i1] = make_float2(dx * wc - dy * ws, dx * ws + dy * wc);
            }
        }
    } else {
#pragma unroll
        for (int s = 0; s < 5; ++s) {
            const int h = 1 << s;
#pragma unroll
            for (int j = 0; j < 16; ++j) {
                const int t = j & (h - 1);
                const int i0 = ((j >> s) << (s + 1)) + t;
                const int i1 = i0 + h;
                const float wc = W32CF_[t << (4 - s)];
                const float ws = W32SF_[t << (4 - s)];
                cf u = a[i0], vr = a[i1];
                cf v = make_float2(vr.x * wc - vr.y * ws, vr.x * ws + vr.y * wc);
                a[i0] = make_float2(u.x + v.x, u.y + v.y);
                a[i1] = make_float2(u.x - v.x, u.y - v.y);
            }
        }
    }
}

// bit-reversed-storage mirror of frequency negation (involution); maps each
// dyadic block [2^s, 2^{s+1}) onto itself -> z half-ranges are mirror-closed.
__device__ __forceinline__ int mir_br(int b) {
    if (b == 0) return 0;
    int s = 31 - __clz(b);
    return (3 << s) - 1 - b;
}

// ---------------------------------------------------------------------------
// K1 (fused): pack h = img + i*tpl + fwd z-FFT, winz fp64 sliding sums,
// tpl fp64 partial sums (block-reduced, no atomics).
__global__ __launch_bounds__(256) void k_pack_stats(const float* __restrict__ img,
                                                    const float* __restrict__ tpl,
                                                    cf* __restrict__ d,
                                                    double* __restrict__ zs1,
                                                    double* __restrict__ zs2,
                                                    double2* __restrict__ part) {
    int line = blockIdx.x * blockDim.x + threadIdx.x;
    long b = (long)line << 5;
    cf a[32];
    const float4* pi4 = (const float4*)(img + b);
    const float4* pt4 = (const float4*)(tpl + b);
#pragma unroll
    for (int q = 0; q < 8; ++q) {
        float4 fi = pi4[q];
        float4 ft = pt4[q];
        a[q * 4 + 0] = make_float2(fi.x, ft.x);
        a[q * 4 + 1] = make_float2(fi.y, ft.y);
        a[q * 4 + 2] = make_float2(fi.z, ft.z);
        a[q * 4 + 3] = make_float2(fi.w, ft.w);
    }
    // --- winz: z sliding-window sums of img, img^2 (fp64) ---
    {
        double s1 = 0, s2 = 0;
#pragma unroll
        for (int z = 0; z < 28; ++z) {
            double t = (double)a[z].x;
            s1 += t; s2 += t * t;
        }
        long ob = (long)line * 5;
        zs1[ob] = s1; zs2[ob] = s2;
#pragma unroll
        for (int k = 1; k <= 4; ++k) {
            double ad = (double)a[27 + k].x, r = (double)a[k - 1].x;
            s1 += ad - r;
            s2 += ad * ad - r * r;
            zs1[ob + k] = s1; zs2[ob + k] = s2;
        }
    }
    // --- tpl partial sums (fp64, block-reduced) ---
    {
        double st = 0, st2 = 0;
#pragma unroll
        for (int z = 0; z < 32; ++z) {
            double t = (double)a[z].y;
            st += t; st2 += t * t;
        }
        __shared__ double r1[256], r2[256];
        int tid = threadIdx.x;
        r1[tid] = st; r2[tid] = st2;
        __syncthreads();
        for (int s = 128; s > 0; s >>= 1) {
            if (tid < s) { r1[tid] += r1[tid + s]; r2[tid] += r2[tid + s]; }
            __syncthreads();
        }
        if (tid == 0) part[blockIdx.x] = make_double2(r1[0], r2[0]);
    }
    // --- pack + forward z-FFT ---
    fft32<0>(a);
#pragma unroll
    for (int z = 0; z < 32; ++z) d[b + z] = a[z];
}

// K3: y-direction sliding window (492 of 512 -> 21)
__global__ __launch_bounds__(256) void k_winy(const double* __restrict__ zs1,
                                              const double* __restrict__ zs2,
                                              double* __restrict__ ys1,
                                              double* __restrict__ ys2) {
    int t = blockIdx.x * blockDim.x + threadIdx.x;
    if (t >= 2560) return;
    int x = t / 5, c = t % 5;
    long base = (long)x * 512 * 5 + c;
    double s1 = 0, s2 = 0;
    for (int y = 0; y < 492; ++y) {
        s1 += zs1[base + (long)y * 5];
        s2 += zs2[base + (long)y * 5];
    }
    long ob = (long)x * 105 + c;
    ys1[ob] = s1; ys2[ob] = s2;
    for (int k = 1; k <= 20; ++k) {
        s1 += zs1[base + (long)(491 + k) * 5] - zs1[base + (long)(k - 1) * 5];
        s2 += zs2[base + (long)(491 + k) * 5] - zs2[base + (long)(k - 1) * 5];
        ys1[ob + (long)k * 5] = s1;
        ys2[ob + (long)k * 5] = s2;
    }
}

// K4: reduce tpl partials -> tpl_var, then x-direction sliding window + denom
__global__ __launch_bounds__(256) void k_winx_denom(const double* __restrict__ ys1,
                                                    const double* __restrict__ ys2,
                                                    const double2* __restrict__ part,
                                                    float* __restrict__ denom) {
    __shared__ double s1s[256], s2s[256];
    __shared__ double tplvar_s;
    int tid = threadIdx.x;
    {
        double a1 = 0, a2 = 0;
#pragma unroll
        for (int q = 0; q < 4; ++q) {
            double2 p = part[tid + 256 * q];
            a1 += p.x; a2 += p.y;
        }
        s1s[tid] = a1; s2s[tid] = a2;
        __syncthreads();
        for (int s = 128; s > 0; s >>= 1) {
            if (tid < s) { s1s[tid] += s1s[tid + s]; s2s[tid] += s2s[tid + s]; }
            __syncthreads();
        }
        if (tid == 0) {
            double S1 = s1s[0], S2 = s2s[0];
            double mu = S1 / (double)NTOT;
            tplvar_s = S2 - (double)NTOT * mu * mu + EPSV;
        }
        __syncthreads();
    }
    if (tid >= 105) return;
    const double tpl_var = tplvar_s;
    double s1 = 0, s2 = 0;
    for (int x = 0; x < 492; ++x) {
        s1 += ys1[(long)x * 105 + tid];
        s2 += ys2[(long)x * 105 + tid];
    }
    const double wm = 1.0 / WIN_PROD;
    for (int a = 0; a < 21; ++a) {
        double m1 = s1 * wm, m2 = s2 * wm;
        double iv = m2 - (m1 * m1) / (double)NTOT + EPSV;
        if (iv < 0) iv = 0;
        denom[a * 105 + tid] = (float)sqrt(tpl_var * iv);
        if (a < 20) {
            s1 += ys1[(long)(492 + a) * 105 + tid] - ys1[(long)a * 105 + tid];
            s2 += ys2[(long)(492 + a) * 105 + tid] - ys2[(long)a * 105 + tid];
        }
    }
}

// ---------------------------------------------------------------------------
// K5/K7: y-direction 512-point line FFT. 16 lines (16 consecutive z) per
// 1024-thread block (one wave per line) -> 128 B global segments.
template <int INV>
__global__ __launch_bounds__(1024, 8) void k_fft16(cf* __restrict__ d) {
    __shared__ cf ln[16][LROW];
    __shared__ cf tw[256];
    const int tid = threadIdx.x;
    if (tid < 256) {
        double sv, cv;
        sincos(6.283185307179586476925286766559 * (double)tid / 512.0, &sv, &cv);
        tw[tid] = make_float2((float)cv, (float)(-sv));   // fwd sign; inv conjugates
    }
    const long base = (long)(blockIdx.x >> 1) * 16384 + (blockIdx.x & 1) * 16;
#pragma unroll
    for (int i = 0; i < 8; ++i) {
        int idx = tid + 1024 * i;
        int lz = idx & 15, e = idx >> 4;          // 16 lanes = 128 B contiguous
        ln[lz][SKW(e)] = d[base + (long)e * 32 + lz];
    }
    __syncthreads();
    const int c = tid >> 6, lane = tid & 63;
    line_fft512<INV>(ln[c], tw, lane);
    __syncthreads();
#pragma unroll
    for (int i = 0; i < 8; ++i) {
        int idx = tid + 1024 * i;
        int lz = idx & 15, e = idx >> 4;
        d[base + (long)e * 32 + lz] = ln[lz][SKW(e)];
    }
}

// ---------------------------------------------------------------------------
// K6: fused forward-x-FFT + cross-power + inverse-x-FFT, v2.
// z half-ranges (bitrev 0..15 / 16..31) are mirror-closed, so pair only in y:
// block = (y, tile) + (mir_br(y), tile). 32 lines x 512, 128 B global segments.
// Crosspow: each thread owns the pair {A(a,bx), B(am,mbx)} for both reads and
// writes (bijection) -> race-free, including self-dup (y==mir_br(y)) blocks.
__global__ __launch_bounds__(1024, 4) void k_fftx_cross(cf* __restrict__ d) {
    const int bid = blockIdx.x;
    const int y = bid >> 1, tile = bid & 1;
    const int my = mir_br(y);
    if (y > my) return;                           // canonical pair only
    const bool dup = (y == my);

    __shared__ cf ln[32][LROW];                   // 148.5 KB
    __shared__ cf tw[256];
    const int tid = threadIdx.x;
    if (tid < 256) {
        double sv, cv;
        sincos(6.283185307179586476925286766559 * (double)tid / 512.0, &sv, &cv);
        tw[tid] = make_float2((float)cv, (float)(-sv));
    }
    const int baseA = y * 32 + tile * 16;
    const int baseB = my * 32 + tile * 16;
#pragma unroll
    for (int i = 0; i < 16; ++i) {
        int idx = tid + 1024 * i;
        int lz = idx & 15, half = (idx >> 4) & 1, bx = idx >> 5;
        ln[half * 16 + lz][SKW(bx)] = d[(long)bx * 16384 + (half ? baseB : baseA) + lz];
    }
    __syncthreads();
    const int c = tid >> 6, lane = tid & 63;
    line_fft512<0>(ln[c], tw, lane);
    line_fft512<0>(ln[16 + c], tw, lane);
    __syncthreads();
    // cross-power: H = F + iG packed; P = F*conj(G); P(-k) = conj(P(k)).
    // tile0 z-mirror within tile: mir_br(a); tile1: global 47-(16+a) -> 15-a.
    const bool dcblk = (bid == 0);
#pragma unroll
    for (int i = 0; i < 8; ++i) {
        int p = tid + 1024 * i;                   // 0..8191 (A-half points)
        int a = p >> 9, bx = p & 511;
        int am = (tile == 0) ? mir_br(a) : 15 - a;
        int mbx = mir_br(bx);
        if (dcblk && p == 0) {                    // zero-mean => DC bin = 0
            ln[0][0] = make_float2(0.f, 0.f);
            ln[16][0] = make_float2(0.f, 0.f);
            continue;
        }
        cf h1 = ln[a][SKW(bx)];
        cf h2 = ln[16 + am][SKW(mbx)];
        float Fr = 0.5f * (h1.x + h2.x), Fi = 0.5f * (h1.y - h2.y);
        float Gr = 0.5f * (h1.y + h2.y), Gi = 0.5f * (h2.x - h1.x);
        float Pr = Fr * Gr + Fi * Gi;
        float Pi = Fi * Gr - Fr * Gi;
        ln[a][SKW(bx)] = make_float2(Pr, Pi);
        ln[16 + am][SKW(mbx)] = make_float2(Pr, -Pi);
    }
    __syncthreads();
    line_fft512<1>(ln[c], tw, lane);
    line_fft512<1>(ln[16 + c], tw, lane);
    __syncthreads();
#pragma unroll
    for (int i = 0; i < 16; ++i) {
        int idx = tid + 1024 * i;
        int lz = idx & 15, half = (idx >> 4) & 1, bx = idx >> 5;
        if (dup && half) continue;                // self-paired: skip dup stores
        d[(long)bx * 16384 + (half ? baseB : baseA) + lz] = ln[half * 16 + lz][SKW(bx)];
    }
}

// ---------------------------------------------------------------------------
// K8: inverse DIT FFT along z, |.|/N, roll by (256,256,16), write rolled_cc
__global__ __launch_bounds__(256) void k_invz_abs_roll(const cf* __restrict__ d,
                                                       float* __restrict__ out) {
    int line = blockIdx.x * blockDim.x + threadIdx.x;
    int x = line >> 9, y = line & 511;
    long b = (long)line << 5;
    cf a[32];
    const float4* p4 = (const float4*)(d + b);
#pragma unroll
    for (int q = 0; q < 16; ++q) {
        float4 f = p4[q];
        a[2 * q]     = make_float2(f.x, f.y);
        a[2 * q + 1] = make_float2(f.z, f.w);
    }
    fft32<1>(a);
    const float invN = 1.0f / 8388608.0f;
    int xo = (x + 256) & 511, yo = (y + 256) & 511;
    long ob = OUT_ROLL_OFF + ((long)(xo << 9 | yo) << 5);
#pragma unroll
    for (int q = 0; q < 8; ++q) {
        int z = q * 4;
        int zo = (z + 16) & 31;
        float4 w;
        w.x = sqrtf(a[z + 0].x * a[z + 0].x + a[z + 0].y * a[z + 0].y) * invN;
        w.y = sqrtf(a[z + 1].x * a[z + 1].x + a[z + 1].y * a[z + 1].y) * invN;
        w.z = sqrtf(a[z + 2].x * a[z + 2].x + a[z + 2].y * a[z + 2].y) * invN;
        w.w = sqrtf(a[z + 3].x * a[z + 3].x + a[z + 3].y * a[z + 3].y) * invN;
        *(float4*)(out + ob + zo) = w;
    }
}

// ---------------------------------------------------------------------------
// K9: fused ncc + argmax (first-max) + log-Gaussian subpixel refine
__global__ __launch_bounds__(256) void k_ncc_argmax(const float* __restrict__ denom,
                                                    float* __restrict__ out) {
    __shared__ float sncc[2205];
    __shared__ float bv[256];
    __shared__ int bi[256];
    const int tid = threadIdx.x;
    float best = -INFINITY;
    int bidx = 0x7fffffff;
    for (int i = tid; i < 2205; i += 256) {
        int a = i / 105, r = i % 105;
        int bq = r / 5, cq = r % 5;
        long ridx = OUT_ROLL_OFF + ((long)((246 + a) * 512 + (246 + bq)) << 5) + (14 + cq);
        float v = out[ridx] / denom[i];
        if (isnan(v)) v = 0.f;
        out[OUT_NCC_OFF + i] = v;
        sncc[i] = v;
        if (v > best) { best = v; bidx = i; }
    }
    bv[tid] = best;
    bi[tid] = bidx;
    __syncthreads();
    for (int s = 128; s > 0; s >>= 1) {
        if (tid < s) {
            if (bv[tid + s] > bv[tid] || (bv[tid + s] == bv[tid] && bi[tid + s] < bi[tid])) {
                bv[tid] = bv[tid + s];
                bi[tid] = bi[tid + s];
            }
        }
        __syncthreads();
    }
    if (tid == 0) {
        int idx = bi[0];
        int sx = idx / 105, sy = (idx % 105) / 5, sz = idx % 5;
        auto cl = [](int v, int n) { return v < 0 ? 0 : (v >= n ? n - 1 : v); };
        auto V = [&](int dx, int dy, int dz) {
            return logf(sncc[cl(sx + dx, 21) * 105 + cl(sy + dy, 21) * 5 + cl(sz + dz, 5)]);
        };
        float v0 = V(0, 0, 0);
        float six = 6.0f * v0;
        float am = V(-1, 0, 0), ap = V(1, 0, 0);
        float bm = V(0, -1, 0), bp = V(0, 1, 0);
        float cm = V(0, 0, -1), cp = V(0, 0, 1);
        out[0] = (float)(-(sx - 10)) - (am - ap) / (2.f * am - six + 2.f * ap);
        out[1] = (float)(-(sy - 10)) - (bm - bp) / (2.f * bm - six + 2.f * bp);
        out[2] = (float)(-(sz - 2)) - (cm - cp) / (2.f * cm - six + 2.f * cp);
    }
}

// ---------------------------------------------------------------------------
extern "C" void kernel_launch(void* const* d_in, const int* in_sizes, int n_in,
                              void* d_out, int out_size, void* d_ws, size_t ws_size,
                              hipStream_t stream) {
    const float* fr = (const float*)d_in[0];
    const float* tpl = (const float*)d_in[1];
    float* out = (float*)d_out;
    char* ws = (char*)d_ws;

    cf* Hc = (cf*)(ws + WS_HC_OFF);
    double* zs1 = (double*)(ws + WS_ZS1_OFF);
    double* zs2 = (double*)(ws + WS_ZS2_OFF);
    double* ys1 = (double*)(ws + WS_YS1_OFF);
    double* ys2 = (double*)(ws + WS_YS2_OFF);
    double2* part = (double2*)(ws + WS_PART_OFF);
    float* denom = (float*)(ws + WS_DENOM_OFF);

    // fused pack + z-FFT + winz + tpl stats
    k_pack_stats<<<NLINES / 256, 256, 0, stream>>>(fr, tpl, Hc, zs1, zs2, part);

    // windowed means -> denominator (independent of FFT chain)
    k_winy<<<10, 256, 0, stream>>>(zs1, zs2, ys1, ys2);
    k_winx_denom<<<1, 256, 0, stream>>>(ys1, ys2, part, denom);

    // forward y-FFT
    k_fft16<0><<<1024, 1024, 0, stream>>>(Hc);

    // fused fwd-x-FFT + cross-power (+DC zero) + inv-x-FFT (y-paired, 16-z tiles)
    k_fftx_cross<<<1024, 1024, 0, stream>>>(Hc);

    // inverse y-FFT, then z-FFT fused with abs+roll+output
    k_fft16<1><<<1024, 1024, 0, stream>>>(Hc);
    k_invz_abs_roll<<<NLINES / 256, 256, 0, stream>>>(Hc, out);

    // ncc + argmax/subpixel (fused)
    k_ncc_argmax<<<1, 256, 0, stream>>>(denom, out);
}

// Round 9
// 367.740 us; speedup vs baseline: 1.7827x; 1.0684x over previous
//
#include <hip/hip_runtime.h>
#include <hip/hip_bf16.h>
#include <math.h>

// ---------------------------------------------------------------------------
// MotionCorrect: FFT-based NCC on 512x512x32 volume (fp32 FFT path, fp64 stats).
//   out = [sh_x, sh_y, sh_z, rolled_cc(512*512*32), ncc(21*21*5)]
// ---------------------------------------------------------------------------

#define NTOT 8388608            // 512*512*32
#define NLINES 262144           // 512*512
#define OUT_ROLL_OFF 3
#define OUT_NCC_OFF 8388611     // 3 + NTOT
#define WIN_PROD 6777792.0      // 492*492*28
#define EPSV 1e-8

// ws layout (bytes)
#define WS_HC_OFF 0UL                       // float2[NTOT] = 67108864 B
#define WS_ZS1_OFF 67108864UL               // double[NLINES*5] = 10485760 B
#define WS_ZS2_OFF 77594624UL
#define WS_YS1_OFF 88080384UL               // double[512*105] = 430080 B
#define WS_YS2_OFF 88510464UL
#define WS_PART_OFF 88940544UL              // double2[1024]
#define WS_DENOM_OFF 88957952UL             // float[2205]

typedef float2 cf;
__device__ __forceinline__ cf cfadd(cf a, cf b){ return make_float2(a.x+b.x, a.y+b.y); }
__device__ __forceinline__ cf cfsub(cf a, cf b){ return make_float2(a.x-b.x, a.y-b.y); }
__device__ __forceinline__ cf cfmul(cf a, cf b){ return make_float2(a.x*b.x-a.y*b.y, a.x*b.y+a.y*b.x); }
__device__ __forceinline__ cf cfnegi(cf a){ return make_float2(a.y, -a.x); }   // a * (-i)
__device__ __forceinline__ cf cfposi(cf a){ return make_float2(-a.y, a.x); }   // a * (+i)

#define RT2F 0.70710678118654752440f
// forward eighth-turns: e^{-i pi/4}, e^{-i 3pi/4}
__device__ __forceinline__ cf cw64f(cf v){ return make_float2(RT2F*(v.x+v.y), RT2F*(v.y-v.x)); }
__device__ __forceinline__ cf cw192f(cf v){ return make_float2(RT2F*(v.y-v.x), -RT2F*(v.x+v.y)); }
// inverse eighth-turns: e^{+i pi/4}, e^{+i 3pi/4}
__device__ __forceinline__ cf cw64i(cf v){ return make_float2(RT2F*(v.x-v.y), RT2F*(v.x+v.y)); }
__device__ __forceinline__ cf cw192i(cf v){ return make_float2(-RT2F*(v.x+v.y), RT2F*(v.x-v.y)); }

// Skewed LDS layout (float2 units): one pad slot between 8-blocks.
#define SKW(i) ((i) + ((i) >> 3))
#define LROW 580                 // >= SKW(511)=574

// ---------------------------------------------------------------------------
// Radix-8 LDS pass, forward DIF, merged stages (4H, 2H, H). One group/lane.
// In-place radix-2 DIF rule: diff output at slot i+h gets W_{2h}^{i mod h}.
// Group base twiddle w = W_{8H}^t = W512^{t*64/H}:
//   stage 4H: diff_m *= W8^m * w ; stage 2H: diffs *= (W4^m) * w^2 ; stage H: *= w^4.
// H=1 (w=1) reduces exactly to fwd_r8 below (bench-verified).
template <int H>
__device__ __forceinline__ void fwd_r8p(cf* ln, const cf* tw, int lane) {
    const int t = lane & (H - 1);
    const int i0 = ((lane & ~(H - 1)) << 3) + t;
    cf x0 = ln[SKW(i0)];
    cf x1 = ln[SKW(i0 + H)];
    cf x2 = ln[SKW(i0 + 2 * H)];
    cf x3 = ln[SKW(i0 + 3 * H)];
    cf x4 = ln[SKW(i0 + 4 * H)];
    cf x5 = ln[SKW(i0 + 5 * H)];
    cf x6 = ln[SKW(i0 + 6 * H)];
    cf x7 = ln[SKW(i0 + 7 * H)];
    cf w  = tw[t * (64 / H)];
    cf w2 = cfmul(w, w);
    cf w4 = cfmul(w2, w2);
    // stage 4H
    cf s0 = cfadd(x0, x4), d0 = cfmul(cfsub(x0, x4), w);
    cf s1 = cfadd(x1, x5), d1 = cfmul(cw64f(cfsub(x1, x5)), w);
    cf s2 = cfadd(x2, x6), d2 = cfmul(cfnegi(cfsub(x2, x6)), w);
    cf s3 = cfadd(x3, x7), d3 = cfmul(cw192f(cfsub(x3, x7)), w);
    // stage 2H
    cf e0 = cfadd(s0, s2), E0 = cfmul(cfsub(s0, s2), w2);
    cf e1 = cfadd(s1, s3), E1 = cfmul(cfnegi(cfsub(s1, s3)), w2);
    cf f0 = cfadd(d0, d2), F0 = cfmul(cfsub(d0, d2), w2);
    cf f1 = cfadd(d1, d3), F1 = cfmul(cfnegi(cfsub(d1, d3)), w2);
    // stage H
    ln[SKW(i0)]         = cfadd(e0, e1);
    ln[SKW(i0 + H)]     = cfmul(cfsub(e0, e1), w4);
    ln[SKW(i0 + 2 * H)] = cfadd(E0, E1);
    ln[SKW(i0 + 3 * H)] = cfmul(cfsub(E0, E1), w4);
    ln[SKW(i0 + 4 * H)] = cfadd(f0, f1);
    ln[SKW(i0 + 5 * H)] = cfmul(cfsub(f0, f1), w4);
    ln[SKW(i0 + 6 * H)] = cfadd(F0, F1);
    ln[SKW(i0 + 7 * H)] = cfmul(cfsub(F0, F1), w4);
}

// Radix-8 LDS pass, inverse DIT, merged stages (H, 2H, 4H), conjugate twiddles.
// Mirrors fwd_r8p reversed; H=1 reduces exactly to inv_r8.
template <int H>
__device__ __forceinline__ void inv_r8p(cf* ln, const cf* tw, int lane) {
    const int t = lane & (H - 1);
    const int i0 = ((lane & ~(H - 1)) << 3) + t;
    cf x0 = ln[SKW(i0)];
    cf x1 = ln[SKW(i0 + H)];
    cf x2 = ln[SKW(i0 + 2 * H)];
    cf x3 = ln[SKW(i0 + 3 * H)];
    cf x4 = ln[SKW(i0 + 4 * H)];
    cf x5 = ln[SKW(i0 + 5 * H)];
    cf x6 = ln[SKW(i0 + 6 * H)];
    cf x7 = ln[SKW(i0 + 7 * H)];
    cf wf = tw[t * (64 / H)];
    cf w  = make_float2(wf.x, -wf.y);   // conj -> W^{+}
    cf w2 = cfmul(w, w);
    cf w4 = cfmul(w2, w2);
    // stage H: odd-slot twiddle w^4
    cf t1 = cfmul(x1, w4); cf a0 = cfadd(x0, t1), a1 = cfsub(x0, t1);
    cf t3 = cfmul(x3, w4); cf a2 = cfadd(x2, t3), a3 = cfsub(x2, t3);
    cf t5 = cfmul(x5, w4); cf a4 = cfadd(x4, t5), a5 = cfsub(x4, t5);
    cf t7 = cfmul(x7, w4); cf a6 = cfadd(x6, t7), a7 = cfsub(x6, t7);
    // stage 2H: slots (m+2) twiddle W4^{+m} * w^2
    cf u2 = cfmul(a2, w2);         cf b0 = cfadd(a0, u2), b2 = cfsub(a0, u2);
    cf u3 = cfposi(cfmul(a3, w2)); cf b1 = cfadd(a1, u3), b3 = cfsub(a1, u3);
    cf u6 = cfmul(a6, w2);         cf b4 = cfadd(a4, u6), b6 = cfsub(a4, u6);
    cf u7 = cfposi(cfmul(a7, w2)); cf b5 = cfadd(a5, u7), b7 = cfsub(a5, u7);
    // stage 4H: slots (m+4) twiddle W8^{+m} * w
    cf v0 = cfmul(b4, w);
    cf v1 = cfmul(cw64i(b5), w);
    cf v2 = cfmul(cfposi(b6), w);
    cf v3 = cfmul(cw192i(b7), w);
    ln[SKW(i0)]         = cfadd(b0, v0);
    ln[SKW(i0 + 4 * H)] = cfsub(b0, v0);
    ln[SKW(i0 + H)]     = cfadd(b1, v1);
    ln[SKW(i0 + 5 * H)] = cfsub(b1, v1);
    ln[SKW(i0 + 2 * H)] = cfadd(b2, v2);
    ln[SKW(i0 + 6 * H)] = cfsub(b2, v2);
    ln[SKW(i0 + 3 * H)] = cfadd(b3, v3);
    ln[SKW(i0 + 7 * H)] = cfsub(b3, v3);
}

// Register radix-8 tail (H=1, w=1): contiguous 8-blocks at [9k, 9k+8).
__device__ __forceinline__ void fwd_r8(cf* ln, int lane) {
    cf* rp = ln + 9 * lane;
    cf L0 = rp[0], L1 = rp[1], L2 = rp[2], L3 = rp[3];
    cf L4 = rp[4], L5 = rp[5], L6 = rp[6], L7 = rp[7];
    cf s0 = cfadd(L0, L4), d0 = cfsub(L0, L4);
    cf s1 = cfadd(L1, L5), d1 = cw64f(cfsub(L1, L5));
    cf s2 = cfadd(L2, L6), d2 = cfnegi(cfsub(L2, L6));
    cf s3 = cfadd(L3, L7), d3 = cw192f(cfsub(L3, L7));
    cf e0 = cfadd(s0, s2), e2 = cfsub(s0, s2);
    cf e1 = cfadd(s1, s3), e3 = cfnegi(cfsub(s1, s3));
    cf f0 = cfadd(d0, d2), f2 = cfsub(d0, d2);
    cf f1 = cfadd(d1, d3), f3 = cfnegi(cfsub(d1, d3));
    rp[0] = cfadd(e0, e1); rp[1] = cfsub(e0, e1);
    rp[2] = cfadd(e2, e3); rp[3] = cfsub(e2, e3);
    rp[4] = cfadd(f0, f1); rp[5] = cfsub(f0, f1);
    rp[6] = cfadd(f2, f3); rp[7] = cfsub(f2, f3);
}

__device__ __forceinline__ void inv_r8(cf* ln, int lane) {
    cf* rp = ln + 9 * lane;
    cf L0 = rp[0], L1 = rp[1], L2 = rp[2], L3 = rp[3];
    cf L4 = rp[4], L5 = rp[5], L6 = rp[6], L7 = rp[7];
    cf a0 = cfadd(L0, L1), a1 = cfsub(L0, L1), a2 = cfadd(L2, L3), a3 = cfsub(L2, L3);
    cf a4 = cfadd(L4, L5), a5 = cfsub(L4, L5), a6 = cfadd(L6, L7), a7 = cfsub(L6, L7);
    cf b0 = cfadd(a0, a2), b2 = cfsub(a0, a2);
    cf v13 = cfposi(a3);
    cf b1 = cfadd(a1, v13), b3 = cfsub(a1, v13);
    cf b4 = cfadd(a4, a6), b6 = cfsub(a4, a6);
    cf v57 = cfposi(a7);
    cf b5 = cfadd(a5, v57), b7 = cfsub(a5, v57);
    cf v0 = b4, v1 = cw64i(b5), v2 = cfposi(b6), v3 = cw192i(b7);
    rp[0] = cfadd(b0, v0); rp[4] = cfsub(b0, v0);
    rp[1] = cfadd(b1, v1); rp[5] = cfsub(b1, v1);
    rp[2] = cfadd(b2, v2); rp[6] = cfsub(b2, v2);
    rp[3] = cfadd(b3, v3); rp[7] = cfsub(b3, v3);
}

// full 512-point line FFT: 512 = 8*8*8 -> 3 radix-8 passes.
// One wave per line; wave_barrier pins cross-lane LDS handoff between passes.
template <int INV>
__device__ __forceinline__ void line_fft512(cf* ln, const cf* tw, int lane) {
    if (!INV) {
        fwd_r8p<64>(ln, tw, lane);     // stages 256,128,64
        __builtin_amdgcn_wave_barrier();
        fwd_r8p<8>(ln, tw, lane);      // stages 32,16,8
        __builtin_amdgcn_wave_barrier();
        fwd_r8(ln, lane);              // stages 4,2,1
    } else {
        inv_r8(ln, lane);              // stages 1,2,4
        __builtin_amdgcn_wave_barrier();
        inv_r8p<8>(ln, tw, lane);      // stages 8,16,32
        __builtin_amdgcn_wave_barrier();
        inv_r8p<64>(ln, tw, lane);     // stages 64,128,256
    }
}

// ---------------------------------------------------------------------------
// per-thread radix-2 FFT of length 32 (z-axis), fp32
static constexpr float W32CF_[16] = {
    1.0f, 0.980785280403230449f, 0.923879532511286756f, 0.831469612302545237f,
    0.707106781186547524f, 0.555570233019602225f, 0.382683432365089772f, 0.195090322016128268f,
    0.0f, -0.195090322016128268f, -0.382683432365089772f, -0.555570233019602225f,
    -0.707106781186547524f, -0.831469612302545237f, -0.923879532511286756f, -0.980785280403230449f};
static constexpr float W32SF_[16] = {
    0.0f, 0.195090322016128268f, 0.382683432365089772f, 0.555570233019602225f,
    0.707106781186547524f, 0.831469612302545237f, 0.923879532511286756f, 0.980785280403230449f,
    1.0f, 0.980785280403230449f, 0.923879532511286756f, 0.831469612302545237f,
    0.707106781186547524f, 0.555570233019602225f, 0.382683432365089772f, 0.195090322016128268f};

template <int INV>
__device__ __forceinline__ void fft32(cf* a) {
    if (INV == 0) {
#pragma unroll
        for (int s = 0; s < 5; ++s) {
            const int h = 16 >> s;
#pragma unroll
            for (int j = 0; j < 16; ++j) {
                const int t = j & (h - 1);
                const int i0 = ((j >> (4 - s)) << (5 - s)) + t;
                const int i1 = i0 + h;
                cf u = a[i0], v = a[i1];
                a[i0] = make_float2(u.x + v.x, u.y + v.y);
                float dx = u.x - v.x, dy = u.y - v.y;
                const float wc = W32CF_[t << s];
                const float ws = -W32SF_[t << s];
                a[i1] = make_float2(dx * wc - dy * ws, dx * ws + dy * wc);
            }
        }
    } else {
#pragma unroll
        for (int s = 0; s < 5; ++s) {
            const int h = 1 << s;
#pragma unroll
            for (int j = 0; j < 16; ++j) {
                const int t = j & (h - 1);
                const int i0 = ((j >> s) << (s + 1)) + t;
                const int i1 = i0 + h;
                const float wc = W32CF_[t << (4 - s)];
                const float ws = W32SF_[t << (4 - s)];
                cf u = a[i0], vr = a[i1];
                cf v = make_float2(vr.x * wc - vr.y * ws, vr.x * ws + vr.y * wc);
                a[i0] = make_float2(u.x + v.x, u.y + v.y);
                a[i1] = make_float2(u.x - v.x, u.y - v.y);
            }
        }
    }
}

// bit-reversed-storage mirror of frequency negation (involution per dyadic block)
__device__ __forceinline__ int mir_br(int b) {
    if (b == 0) return 0;
    int s = 31 - __clz(b);
    return (3 << s) - 1 - b;
}

// ---------------------------------------------------------------------------
// K1 (fused): pack h = img + i*tpl + fwd z-FFT, winz fp64 sliding sums,
// tpl fp64 partial sums (block-reduced, no atomics).
__global__ __launch_bounds__(256) void k_pack_stats(const float* __restrict__ img,
                                                    const float* __restrict__ tpl,
                                                    cf* __restrict__ d,
                                                    double* __restrict__ zs1,
                                                    double* __restrict__ zs2,
                                                    double2* __restrict__ part) {
    int line = blockIdx.x * blockDim.x + threadIdx.x;
    long b = (long)line << 5;
    cf a[32];
    const float4* pi4 = (const float4*)(img + b);
    const float4* pt4 = (const float4*)(tpl + b);
#pragma unroll
    for (int q = 0; q < 8; ++q) {
        float4 fi = pi4[q];
        float4 ft = pt4[q];
        a[q * 4 + 0] = make_float2(fi.x, ft.x);
        a[q * 4 + 1] = make_float2(fi.y, ft.y);
        a[q * 4 + 2] = make_float2(fi.z, ft.z);
        a[q * 4 + 3] = make_float2(fi.w, ft.w);
    }
    // winz: z sliding-window sums of img, img^2 (fp64)
    {
        double s1 = 0, s2 = 0;
#pragma unroll
        for (int z = 0; z < 28; ++z) {
            double t = (double)a[z].x;
            s1 += t; s2 += t * t;
        }
        long ob = (long)line * 5;
        zs1[ob] = s1; zs2[ob] = s2;
#pragma unroll
        for (int k = 1; k <= 4; ++k) {
            double ad = (double)a[27 + k].x, r = (double)a[k - 1].x;
            s1 += ad - r;
            s2 += ad * ad - r * r;
            zs1[ob + k] = s1; zs2[ob + k] = s2;
        }
    }
    // tpl partial sums (fp64, block-reduced)
    {
        double st = 0, st2 = 0;
#pragma unroll
        for (int z = 0; z < 32; ++z) {
            double t = (double)a[z].y;
            st += t; st2 += t * t;
        }
        __shared__ double r1[256], r2[256];
        int tid = threadIdx.x;
        r1[tid] = st; r2[tid] = st2;
        __syncthreads();
        for (int s = 128; s > 0; s >>= 1) {
            if (tid < s) { r1[tid] += r1[tid + s]; r2[tid] += r2[tid + s]; }
            __syncthreads();
        }
        if (tid == 0) part[blockIdx.x] = make_double2(r1[0], r2[0]);
    }
    // pack + forward z-FFT
    fft32<0>(a);
#pragma unroll
    for (int z = 0; z < 32; ++z) d[b + z] = a[z];
}

// K3: y-direction sliding window (492 of 512 -> 21)
__global__ __launch_bounds__(256) void k_winy(const double* __restrict__ zs1,
                                              const double* __restrict__ zs2,
                                              double* __restrict__ ys1,
                                              double* __restrict__ ys2) {
    int t = blockIdx.x * blockDim.x + threadIdx.x;
    if (t >= 2560) return;
    int x = t / 5, c = t % 5;
    long base = (long)x * 512 * 5 + c;
    double s1 = 0, s2 = 0;
    for (int y = 0; y < 492; ++y) {
        s1 += zs1[base + (long)y * 5];
        s2 += zs2[base + (long)y * 5];
    }
    long ob = (long)x * 105 + c;
    ys1[ob] = s1; ys2[ob] = s2;
    for (int k = 1; k <= 20; ++k) {
        s1 += zs1[base + (long)(491 + k) * 5] - zs1[base + (long)(k - 1) * 5];
        s2 += zs2[base + (long)(491 + k) * 5] - zs2[base + (long)(k - 1) * 5];
        ys1[ob + (long)k * 5] = s1;
        ys2[ob + (long)k * 5] = s2;
    }
}

// K4: reduce tpl partials -> tpl_var, then x-direction sliding window + denom
__global__ __launch_bounds__(256) void k_winx_denom(const double* __restrict__ ys1,
                                                    const double* __restrict__ ys2,
                                                    const double2* __restrict__ part,
                                                    float* __restrict__ denom) {
    __shared__ double s1s[256], s2s[256];
    __shared__ double tplvar_s;
    int tid = threadIdx.x;
    {
        double a1 = 0, a2 = 0;
#pragma unroll
        for (int q = 0; q < 4; ++q) {
            double2 p = part[tid + 256 * q];
            a1 += p.x; a2 += p.y;
        }
        s1s[tid] = a1; s2s[tid] = a2;
        __syncthreads();
        for (int s = 128; s > 0; s >>= 1) {
            if (tid < s) { s1s[tid] += s1s[tid + s]; s2s[tid] += s2s[tid + s]; }
            __syncthreads();
        }
        if (tid == 0) {
            double S1 = s1s[0], S2 = s2s[0];
            double mu = S1 / (double)NTOT;
            tplvar_s = S2 - (double)NTOT * mu * mu + EPSV;
        }
        __syncthreads();
    }
    if (tid >= 105) return;
    const double tpl_var = tplvar_s;
    double s1 = 0, s2 = 0;
    for (int x = 0; x < 492; ++x) {
        s1 += ys1[(long)x * 105 + tid];
        s2 += ys2[(long)x * 105 + tid];
    }
    const double wm = 1.0 / WIN_PROD;
    for (int a = 0; a < 21; ++a) {
        double m1 = s1 * wm, m2 = s2 * wm;
        double iv = m2 - (m1 * m1) / (double)NTOT + EPSV;
        if (iv < 0) iv = 0;
        denom[a * 105 + tid] = (float)sqrt(tpl_var * iv);
        if (a < 20) {
            s1 += ys1[(long)(492 + a) * 105 + tid] - ys1[(long)a * 105 + tid];
            s2 += ys2[(long)(492 + a) * 105 + tid] - ys2[(long)a * 105 + tid];
        }
    }
}

// ---------------------------------------------------------------------------
// K5/K7: y-direction 512-point line FFT. 16 lines (16 consecutive z) per
// 1024-thread block (one wave per line) -> 128 B global segments.
template <int INV>
__global__ __launch_bounds__(1024, 8) void k_fft16(cf* __restrict__ d) {
    __shared__ cf ln[16][LROW];
    __shared__ cf tw[256];
    const int tid = threadIdx.x;
    if (tid < 256) {
        double sv, cv;
        sincos(6.283185307179586476925286766559 * (double)tid / 512.0, &sv, &cv);
        tw[tid] = make_float2((float)cv, (float)(-sv));   // fwd sign; inv conjugates
    }
    const long base = (long)(blockIdx.x >> 1) * 16384 + (blockIdx.x & 1) * 16;
#pragma unroll
    for (int i = 0; i < 8; ++i) {
        int idx = tid + 1024 * i;
        int lz = idx & 15, e = idx >> 4;          // 16 lanes = 128 B contiguous
        ln[lz][SKW(e)] = d[base + (long)e * 32 + lz];
    }
    __syncthreads();
    const int c = tid >> 6, lane = tid & 63;
    line_fft512<INV>(ln[c], tw, lane);
    __syncthreads();
#pragma unroll
    for (int i = 0; i < 8; ++i) {
        int idx = tid + 1024 * i;
        int lz = idx & 15, e = idx >> 4;
        d[base + (long)e * 32 + lz] = ln[lz][SKW(e)];
    }
}

// ---------------------------------------------------------------------------
// K6: fused forward-x-FFT + cross-power + inverse-x-FFT (round-5 structure:
// 8-z tiles, 76 KB LDS -> 2 blocks/CU). Block pairs A=(y, 8-z tile tA) with
// B=(mir_br(y), tB), tB = tA^(tA>>1) ({0,1,3,2}); within-tile line mirror:
// tile0 -> mir_br(a), tiles 1..3 -> 7-a. x-mirror local in bitrev order.
__global__ __launch_bounds__(1024, 4) void k_fftx_cross(cf* __restrict__ d) {
    const int bid = blockIdx.x;
    const int y = bid >> 2, tA = bid & 3;
    const int my = mir_br(y);
    const int tB = tA ^ (tA >> 1);
    const int keyA = (y << 2) | tA, keyB = (my << 2) | tB;
    if (keyA > keyB) return;                      // canonical pair only
    const bool dup = (keyA == keyB);

    __shared__ cf ln[16][LROW];
    __shared__ cf tw[256];
    const int tid = threadIdx.x;
    if (tid < 256) {
        double sv, cv;
        sincos(6.283185307179586476925286766559 * (double)tid / 512.0, &sv, &cv);
        tw[tid] = make_float2((float)cv, (float)(-sv));
    }
    const int baseA = y * 32 + tA * 8;
    const int baseB = my * 32 + tB * 8;
#pragma unroll
    for (int i = 0; i < 8; ++i) {
        int idx = tid + 1024 * i;
        int a = idx & 7, half = (idx >> 3) & 1, bx = idx >> 4;
        ln[half * 8 + a][SKW(bx)] = d[(long)bx * 16384 + (half ? baseB : baseA) + a];
    }
    __syncthreads();
    const int c = tid >> 6, lane = tid & 63;
    line_fft512<0>(ln[c], tw, lane);
    __syncthreads();
    // cross-power: H = F + iG packed; P = F*conj(G); P(-k) = conj(P(k)).
    // A-rows [0..7] sources, partners written into B-rows [8..15]; the map
    // (a,bx)->(am,mbx) is a bijection -> race-free (incl. dup blocks).
    const bool dcblk = (bid == 0);
#pragma unroll
    for (int i = 0; i < 4; ++i) {
        int p = tid + 1024 * i;                   // 0..4095
        int a = p >> 9, bx = p & 511;
        int am = (tA == 0) ? mir_br(a) : 7 - a;
        int mbx = mir_br(bx);
        if (dcblk && p == 0) {                    // zero-mean => DC bin = 0
            ln[0][0] = make_float2(0.f, 0.f);
            ln[8][0] = make_float2(0.f, 0.f);
            continue;
        }
        cf h1 = ln[a][SKW(bx)];
        cf h2 = ln[8 + am][SKW(mbx)];
        float Fr = 0.5f * (h1.x + h2.x), Fi = 0.5f * (h1.y - h2.y);
        float Gr = 0.5f * (h1.y + h2.y), Gi = 0.5f * (h2.x - h1.x);
        float Pr = Fr * Gr + Fi * Gi;
        float Pi = Fi * Gr - Fr * Gi;
        ln[a][SKW(bx)] = make_float2(Pr, Pi);
        ln[8 + am][SKW(mbx)] = make_float2(Pr, -Pi);
    }
    __syncthreads();
    line_fft512<1>(ln[c], tw, lane);
    __syncthreads();
#pragma unroll
    for (int i = 0; i < 8; ++i) {
        int idx = tid + 1024 * i;
        int a = idx & 7, half = (idx >> 3) & 1, bx = idx >> 4;
        if (dup && half) continue;                // self-paired: skip dup stores
        d[(long)bx * 16384 + (half ? baseB : baseA) + a] = ln[half * 8 + a][SKW(bx)];
    }
}

// ---------------------------------------------------------------------------
// K8: inverse DIT FFT along z, |.|/N, roll by (256,256,16), write rolled_cc
__global__ __launch_bounds__(256) void k_invz_abs_roll(const cf* __restrict__ d,
                                                       float* __restrict__ out) {
    int line = blockIdx.x * blockDim.x + threadIdx.x;
    int x = line >> 9, y = line & 511;
    long b = (long)line << 5;
    cf a[32];
    const float4* p4 = (const float4*)(d + b);
#pragma unroll
    for (int q = 0; q < 16; ++q) {
        float4 f = p4[q];
        a[2 * q]     = make_float2(f.x, f.y);
        a[2 * q + 1] = make_float2(f.z, f.w);
    }
    fft32<1>(a);
    const float invN = 1.0f / 8388608.0f;
    int xo = (x + 256) & 511, yo = (y + 256) & 511;
    long ob = OUT_ROLL_OFF + ((long)(xo << 9 | yo) << 5);
#pragma unroll
    for (int q = 0; q < 8; ++q) {
        int z = q * 4;
        int zo = (z + 16) & 31;
        float4 w;
        w.x = sqrtf(a[z + 0].x * a[z + 0].x + a[z + 0].y * a[z + 0].y) * invN;
        w.y = sqrtf(a[z + 1].x * a[z + 1].x + a[z + 1].y * a[z + 1].y) * invN;
        w.z = sqrtf(a[z + 2].x * a[z + 2].x + a[z + 2].y * a[z + 2].y) * invN;
        w.w = sqrtf(a[z + 3].x * a[z + 3].x + a[z + 3].y * a[z + 3].y) * invN;
        *(float4*)(out + ob + zo) = w;
    }
}

// ---------------------------------------------------------------------------
// K9: fused ncc + argmax (first-max) + log-Gaussian subpixel refine
__global__ __launch_bounds__(256) void k_ncc_argmax(const float* __restrict__ denom,
                                                    float* __restrict__ out) {
    __shared__ float sncc[2205];
    __shared__ float bv[256];
    __shared__ int bi[256];
    const int tid = threadIdx.x;
    float best = -INFINITY;
    int bidx = 0x7fffffff;
    for (int i = tid; i < 2205; i += 256) {
        int a = i / 105, r = i % 105;
        int bq = r / 5, cq = r % 5;
        long ridx = OUT_ROLL_OFF + ((long)((246 + a) * 512 + (246 + bq)) << 5) + (14 + cq);
        float v = out[ridx] / denom[i];
        if (isnan(v)) v = 0.f;
        out[OUT_NCC_OFF + i] = v;
        sncc[i] = v;
        if (v > best) { best = v; bidx = i; }
    }
    bv[tid] = best;
    bi[tid] = bidx;
    __syncthreads();
    for (int s = 128; s > 0; s >>= 1) {
        if (tid < s) {
            if (bv[tid + s] > bv[tid] || (bv[tid + s] == bv[tid] && bi[tid + s] < bi[tid])) {
                bv[tid] = bv[tid + s];
                bi[tid] = bi[tid + s];
            }
        }
        __syncthreads();
    }
    if (tid == 0) {
        int idx = bi[0];
        int sx = idx / 105, sy = (idx % 105) / 5, sz = idx % 5;
        auto cl = [](int v, int n) { return v < 0 ? 0 : (v >= n ? n - 1 : v); };
        auto V = [&](int dx, int dy, int dz) {
            return logf(sncc[cl(sx + dx, 21) * 105 + cl(sy + dy, 21) * 5 + cl(sz + dz, 5)]);
        };
        float v0 = V(0, 0, 0);
        float six = 6.0f * v0;
        float am = V(-1, 0, 0), ap = V(1, 0, 0);
        float bm = V(0, -1, 0), bp = V(0, 1, 0);
        float cm = V(0, 0, -1), cp = V(0, 0, 1);
        out[0] = (float)(-(sx - 10)) - (am - ap) / (2.f * am - six + 2.f * ap);
        out[1] = (float)(-(sy - 10)) - (bm - bp) / (2.f * bm - six + 2.f * bp);
        out[2] = (float)(-(sz - 2)) - (cm - cp) / (2.f * cm - six + 2.f * cp);
    }
}

// ---------------------------------------------------------------------------
extern "C" void kernel_launch(void* const* d_in, const int* in_sizes, int n_in,
                              void* d_out, int out_size, void* d_ws, size_t ws_size,
                              hipStream_t stream) {
    const float* fr = (const float*)d_in[0];
    const float* tpl = (const float*)d_in[1];
    float* out = (float*)d_out;
    char* ws = (char*)d_ws;

    cf* Hc = (cf*)(ws + WS_HC_OFF);
    double* zs1 = (double*)(ws + WS_ZS1_OFF);
    double* zs2 = (double*)(ws + WS_ZS2_OFF);
    double* ys1 = (double*)(ws + WS_YS1_OFF);
    double* ys2 = (double*)(ws + WS_YS2_OFF);
    double2* part = (double2*)(ws + WS_PART_OFF);
    float* denom = (float*)(ws + WS_DENOM_OFF);

    // fused pack + z-FFT + winz + tpl stats
    k_pack_stats<<<NLINES / 256, 256, 0, stream>>>(fr, tpl, Hc, zs1, zs2, part);

    // windowed means -> denominator (independent of FFT chain)
    k_winy<<<10, 256, 0, stream>>>(zs1, zs2, ys1, ys2);
    k_winx_denom<<<1, 256, 0, stream>>>(ys1, ys2, part, denom);

    // forward y-FFT
    k_fft16<0><<<1024, 1024, 0, stream>>>(Hc);

    // fused fwd-x-FFT + cross-power (+DC zero) + inv-x-FFT (8-z tiles, 2 blk/CU)
    k_fftx_cross<<<2048, 1024, 0, stream>>>(Hc);

    // inverse y-FFT, then z-FFT fused with abs+roll+output
    k_fft16<1><<<1024, 1024, 0, stream>>>(Hc);
    k_invz_abs_roll<<<NLINES / 256, 256, 0, stream>>>(Hc, out);

    // ncc + argmax/subpixel (fused)
    k_ncc_argmax<<<1, 256, 0, stream>>>(denom, out);
}